// Round 7
// baseline (408.029 us; speedup 1.0000x reference)
//
#include <hip/hip_runtime.h>
#include <math.h>

#define N_NODES 50000
#define SN      N_NODES               // sentinel node id for CSR pads
#define E_RAW   1600000
#define TE      (E_RAW + N_NODES)     // 1650000 edges incl. self loops
#define TEP     (TE + 16 * N_NODES)   // CSR padded to 16-aligned rows (upper bound)
#define F_IN    128
#define H1      4
#define F1      128                   // H1*C1
#define F2      64
#define NEG_SLOPE 0.2f
#define EPS_F   1e-16f
#define XPAD    136                   // LDS row stride in bf16 (kills bank conflicts)
#define LOG2E   1.4426950408889634f
#define NB16_MAX (TEP / 16)           // structural bound: no hang even if deg corrupt

#define NBLK_A  128                   // blocks in deg-atomic pass
#define EPB     ((TE + NBLK_A - 1) / NBLK_A)
#define MM_BLOCKS (N_NODES / 16)      // 3125
#define SC_BLOCKS 2048                // scatter-direct grid

typedef float vf2 __attribute__((ext_vector_type(2)));
typedef short short8 __attribute__((ext_vector_type(8)));
typedef float f32x4 __attribute__((ext_vector_type(4)));

__device__ __forceinline__ unsigned short f2bf(float f) {
    unsigned u = __float_as_uint(f);
    return (unsigned short)((u + 0x7fffu + ((u >> 16) & 1u)) >> 16);
}
__device__ __forceinline__ unsigned char f2fp8(float f) {
    int p = __builtin_amdgcn_cvt_pk_fp8_f32(f, f, 0, false);
    return (unsigned char)(p & 0xff);
}
__device__ __forceinline__ vf2 fp8lo(unsigned u) {   // bytes 0,1 -> 2 floats
    return __builtin_amdgcn_cvt_pk_f32_fp8((int)u, false);
}
__device__ __forceinline__ vf2 fp8hi(unsigned u) {   // bytes 2,3 -> 2 floats
    return __builtin_amdgcn_cvt_pk_f32_fp8((int)u, true);
}
// Packed dual-fp32 FMA; cvt_pk_f32_fp8 already yields float2.
__device__ __forceinline__ vf2 pkfma(float w, vf2 a, vf2 c) {
#if __has_builtin(__builtin_elementwise_fma)
    vf2 wv = {w, w};
    return __builtin_elementwise_fma(wv, a, c);
#else
    c.x = fmaf(w, a.x, c.x);
    c.y = fmaf(w, a.y, c.y);
    return c;
#endif
}
// Raw 2^x (attention logits pre-scaled by log2(e) in the matmul kernels).
__device__ __forceinline__ float fexp2(float x) {
#if __has_builtin(__builtin_amdgcn_exp2f)
    return __builtin_amdgcn_exp2f(x);
#else
    return exp2f(x);
#endif
}

// ---------------- prep: W -> transposed bf16 [c][k]; sentinel logits ---------
__global__ __launch_bounds__(256) void k_prep(const float* __restrict__ W1,
                                              const float* __restrict__ W2,
                                              unsigned short* __restrict__ w1t,
                                              unsigned short* __restrict__ w2t,
                                              float* __restrict__ a1s,
                                              float* __restrict__ a2s,
                                              unsigned* __restrict__ xw1row,
                                              unsigned* __restrict__ xw2row) {
    int idx = blockIdx.x * 256 + threadIdx.x;   // 96 blocks: 16384 + 8192
    if (idx < 16384) {
        int c = idx >> 7, k = idx & 127;
        w1t[idx] = f2bf(W1[k * F1 + c]);
    } else {
        int j = idx - 16384;
        int c = j >> 7, k = j & 127;
        w2t[j] = f2bf(W2[k * F2 + c]);
    }
    if (blockIdx.x == 0 && threadIdx.x < H1) a1s[SN * H1 + threadIdx.x] = -1e30f;
    if (blockIdx.x == 0 && threadIdx.x == H1) a2s[SN] = -1e30f;
    // zero sentinel xw rows: weight 0 * fp8-garbage could be 0*NaN otherwise
    if (blockIdx.x == 1) {
        if (threadIdx.x < 32) xw1row[threadIdx.x] = 0u;
        else if (threadIdx.x < 48) xw2row[threadIdx.x - 32] = 0u;
    }
}

// ---------------- layer1 matmul via MFMA (+ fused deg atomics) ---------------
// CSR chain simplified (round 7): the 128 extra blocks now just atomicAdd
// into deg[] directly (device-scope, ~33 collisions/counter) -- replaces the
// coarse-histogram + btot + bstart + bucket-scatter + fine-hist pipeline.
__global__ __launch_bounds__(256) void k_l1_mm_hist(
    const float* __restrict__ x, const unsigned short* __restrict__ w1t,
    const float* __restrict__ atts, const float* __restrict__ attd,
    unsigned char* __restrict__ xwf8, float* __restrict__ a1s, float* __restrict__ a1d,
    const int* __restrict__ ei, int* __restrict__ deg) {
    __shared__ __align__(16) unsigned short wls[F1 * XPAD];
    __shared__ __align__(16) unsigned short xs[16 * XPAD];
    const int t = threadIdx.x;
    if (blockIdx.x >= MM_BLOCKS) {
        const int blk = blockIdx.x - MM_BLOCKS;
        const int e0 = blk * EPB, e1 = min(TE, e0 + EPB);
        for (int e = e0 + t; e < e1; e += 256) {
            int d = (e < E_RAW) ? ei[E_RAW + e] : (e - E_RAW);
            atomicAdd(&deg[d], 1);
        }
        return;
    }
    const int n0 = blockIdx.x * 16;
    {
        const float4* src = (const float4*)(x + (size_t)n0 * F_IN);
#pragma unroll
        for (int i = 0; i < 2; ++i) {
            int idx = t + 256 * i;
            float4 v = src[idx];
            int row = idx >> 5;
            int col = (idx & 31) * 4;
            ushort4 o = { f2bf(v.x), f2bf(v.y), f2bf(v.z), f2bf(v.w) };
            *(ushort4*)(xs + row * XPAD + col) = o;
        }
        const uint4* wsrc = (const uint4*)w1t;
#pragma unroll
        for (int i = 0; i < 8; ++i) {
            int idx = t + 256 * i;
            uint4 v = wsrc[idx];
            int row = idx >> 4;
            int col = (idx & 15) * 8;
            *(uint4*)(wls + row * XPAD + col) = v;
        }
    }
    __syncthreads();
    const int w = t >> 6;         // wave = head
    const int lane = t & 63;
    const int quad = lane >> 4;
    const int ncol = lane & 15;
    const int ch0 = w * 32;
    const unsigned short* arow = xs + ncol * XPAD;
    const unsigned short* brow0 = wls + (ch0 + ncol) * XPAD;
    const unsigned short* brow1 = brow0 + 16 * XPAD;
    f32x4 acc0 = {0.f, 0.f, 0.f, 0.f}, acc1 = {0.f, 0.f, 0.f, 0.f};
#pragma unroll
    for (int s = 0; s < 4; ++s) {
        int kb = s * 32 + quad * 8;
        short8 a  = *(const short8*)(arow + kb);
        short8 b0 = *(const short8*)(brow0 + kb);
        short8 b1 = *(const short8*)(brow1 + kb);
        acc0 = __builtin_amdgcn_mfma_f32_16x16x32_bf16(a, b0, acc0, 0, 0, 0);
        acc1 = __builtin_amdgcn_mfma_f32_16x16x32_bf16(a, b1, acc1, 0, 0, 0);
    }
    const int ch = ch0 + ncol;
    // logits pre-scaled by log2(e): gather kernels use bare v_exp_f32
    const float as0 = atts[ch] * LOG2E, as1 = atts[ch + 16] * LOG2E;
    const float ad0 = attd[ch] * LOG2E, ad1 = attd[ch + 16] * LOG2E;
#pragma unroll
    for (int reg = 0; reg < 4; ++reg) {
        const int n = n0 + quad * 4 + reg;
        float v0 = acc0[reg], v1 = acc1[reg];
        xwf8[(size_t)n * F1 + ch] = f2fp8(v0);
        xwf8[(size_t)n * F1 + ch + 16] = f2fp8(v1);
        float ps = fmaf(v0, as0, v1 * as1);
        float pd = fmaf(v0, ad0, v1 * ad1);
#pragma unroll
        for (int off = 1; off < 16; off <<= 1) {
            ps += __shfl_xor(ps, off);
            pd += __shfl_xor(pd, off);
        }
        if (ncol == 0) {
            a1s[n * H1 + w] = ps;
            a1d[n * H1 + w] = pd;
        }
    }
}

// ---------------- exclusive scan over 16-PADDED degrees (2-level) ------------
__global__ __launch_bounds__(1024) void k_scan1(const int* __restrict__ deg,
                                                int* __restrict__ incl, int* __restrict__ bsum) {
    int t = threadIdx.x, g = blockIdx.x;
    int idx = g * 1024 + t;
    int v = (idx < N_NODES) ? ((deg[idx] + 15) & ~15) : 0;
    int lane = t & 63, w = t >> 6;
#pragma unroll
    for (int off = 1; off < 64; off <<= 1) {
        int u = __shfl_up(v, off, 64);
        if (lane >= off) v += u;
    }
    __shared__ int ws[16];
    if (lane == 63) ws[w] = v;
    __syncthreads();
    if (w == 0 && lane < 16) {
        int s = ws[lane];
#pragma unroll
        for (int off = 1; off < 16; off <<= 1) {
            int u = __shfl_up(s, off, 16);
            if (lane >= off) s += u;
        }
        ws[lane] = s;
    }
    __syncthreads();
    if (w > 0) v += ws[w - 1];
    if (idx < N_NODES) incl[idx] = v;
    if (t == 1023) bsum[g] = v;
}

// scan3: absorbs scan2 (sums bsum itself), writes rowstart + scatter cursor,
// and pre-fills the sentinel pad region of csr (disjoint from real entries,
// so it can run before the scatter).
__global__ __launch_bounds__(1024) void k_scan3(const int* __restrict__ incl,
                                                const int* __restrict__ bsum,
                                                const int* __restrict__ deg,
                                                int* __restrict__ rowstart,
                                                int* __restrict__ cur,
                                                int* __restrict__ csr) {
    __shared__ int soff;
    const int t = threadIdx.x;
    if (t < 64) {
        int v = (t < blockIdx.x) ? bsum[t] : 0;
#pragma unroll
        for (int off = 32; off >= 1; off >>= 1) v += __shfl_xor(v, off, 64);
        if (t == 0) soff = v;
    }
    __syncthreads();
    const int idx = blockIdx.x * 1024 + t;
    if (idx < N_NODES) {
        const int rend = incl[idx] + soff;            // rowstart[idx+1]
        rowstart[idx + 1] = rend;
        const int d = deg[idx];
        const int rbeg = rend - ((d + 15) & ~15);
        cur[idx] = rbeg;
        for (int i = rbeg + d; i < rend; ++i) csr[i] = SN;
    }
    if (idx == 0) rowstart[0] = 0;
}

// ---------------- direct scatter: ei -> csr via device-atomic cursors --------
// 1.65M atomics over 50k counters (~33 collisions each); scattered 4B csr
// writes are absorbed by L2/L3 (csr = 9.8 MB).
__global__ __launch_bounds__(256) void k_scatter_direct(const int* __restrict__ ei,
                                                        int* __restrict__ cur,
                                                        int* __restrict__ csr) {
    for (int e = blockIdx.x * 256 + threadIdx.x; e < TE; e += SC_BLOCKS * 256) {
        int s, d;
        if (e < E_RAW) { s = ei[e]; d = ei[E_RAW + e]; }
        else { s = e - E_RAW; d = s; }
        int pos = atomicAdd(&cur[d], 1);
        csr[pos] = s;
    }
}

// ---------------- layer1 gather (round-2 form: proven 42.5us, VGPR 32) -------
__global__ __launch_bounds__(256) void k_l1_gather(
    const int* __restrict__ rowstart, const int* __restrict__ csr,
    const int* __restrict__ deg, const float* __restrict__ a1s,
    const float* __restrict__ a1d, const unsigned* __restrict__ xwu,
    const float* __restrict__ b1, float* __restrict__ h1) {
    const int lane = threadIdx.x & 63;
    const int wid = threadIdx.x >> 6;
    const int n = blockIdx.x * 4 + wid;
    if (n >= N_NODES) return;
    const int rs = rowstart[n];
    const int nb16 = min((deg[n] + 15) >> 4, NB16_MAX);
    const int half = lane >> 5;
    const int sub = lane & 31;          // channel group 4*sub..4*sub+3
    const int h = sub >> 3;             // head
    const float adh = a1d[n * H1 + h];
    const int4* c4 = (const int4*)(csr + rs);
    const int eoff = half * 8 + (sub & 7);      // this lane's weight-edge in block
    const int wbase = half * 32 + (h << 3);     // octet's shuffle source base
    vf2 f01 = {0.f, 0.f}, f23 = {0.f, 0.f};
    float den_l = 0.f;
    for (int b = 0; b < nb16; ++b) {
        const int i0 = 4 * b + 2 * half;
        int4 sA = c4[i0], sB = c4[i0 + 1];
        int se = csr[rs + 16 * b + eoff];
        unsigned u0 = xwu[sA.x * 32 + sub], u1 = xwu[sA.y * 32 + sub];
        unsigned u2 = xwu[sA.z * 32 + sub], u3 = xwu[sA.w * 32 + sub];
        unsigned u4 = xwu[sB.x * 32 + sub], u5 = xwu[sB.y * 32 + sub];
        unsigned u6 = xwu[sB.z * 32 + sub], u7 = xwu[sB.w * 32 + sub];
        float sv = a1s[se * H1 + h] + adh;
        float we = fexp2(fmaxf(sv, NEG_SLOPE * sv));
        den_l += we;
        float w0 = __shfl(we, wbase + 0), w1 = __shfl(we, wbase + 1);
        float w2 = __shfl(we, wbase + 2), w3 = __shfl(we, wbase + 3);
        float w4 = __shfl(we, wbase + 4), w5 = __shfl(we, wbase + 5);
        float w6 = __shfl(we, wbase + 6), w7 = __shfl(we, wbase + 7);
        f01 = pkfma(w0, fp8lo(u0), f01); f23 = pkfma(w0, fp8hi(u0), f23);
        f01 = pkfma(w1, fp8lo(u1), f01); f23 = pkfma(w1, fp8hi(u1), f23);
        f01 = pkfma(w2, fp8lo(u2), f01); f23 = pkfma(w2, fp8hi(u2), f23);
        f01 = pkfma(w3, fp8lo(u3), f01); f23 = pkfma(w3, fp8hi(u3), f23);
        f01 = pkfma(w4, fp8lo(u4), f01); f23 = pkfma(w4, fp8hi(u4), f23);
        f01 = pkfma(w5, fp8lo(u5), f01); f23 = pkfma(w5, fp8hi(u5), f23);
        f01 = pkfma(w6, fp8lo(u6), f01); f23 = pkfma(w6, fp8hi(u6), f23);
        f01 = pkfma(w7, fp8lo(u7), f01); f23 = pkfma(w7, fp8hi(u7), f23);
    }
    float f0 = f01.x, f1 = f01.y, f2v = f23.x, f3 = f23.y;
    f0 += __shfl_xor(f0, 32);
    f1 += __shfl_xor(f1, 32);
    f2v += __shfl_xor(f2v, 32);
    f3 += __shfl_xor(f3, 32);
    den_l += __shfl_xor(den_l, 1);
    den_l += __shfl_xor(den_l, 2);
    den_l += __shfl_xor(den_l, 4);
    den_l += __shfl_xor(den_l, 32);
    if (half == 0) {
        const float inv = 1.f / (den_l + EPS_F);
        float4 bb = ((const float4*)b1)[sub];
        float o0 = fmaf(f0, inv, bb.x);
        float o1 = fmaf(f1, inv, bb.y);
        float o2 = fmaf(f2v, inv, bb.z);
        float o3 = fmaf(f3, inv, bb.w);
        o0 = o0 > 0.f ? o0 : expm1f(o0);
        o1 = o1 > 0.f ? o1 : expm1f(o1);
        o2 = o2 > 0.f ? o2 : expm1f(o2);
        o3 = o3 > 0.f ? o3 : expm1f(o3);
        ((float4*)h1)[(size_t)n * 32 + sub] = make_float4(o0, o1, o2, o3);
    }
}

// ---------------- layer2 matmul via MFMA (fp8 out, single head) --------------
__global__ __launch_bounds__(256) void k_l2_mm(
    const float* __restrict__ h1, const unsigned short* __restrict__ w2t,
    const float* __restrict__ atts, const float* __restrict__ attd,
    unsigned char* __restrict__ xwf8, float* __restrict__ a2s, float* __restrict__ a2d) {
    __shared__ __align__(16) unsigned short wls[F2 * XPAD];
    __shared__ __align__(16) unsigned short xs[16 * XPAD];
    __shared__ float parts[16][4], partd[16][4];
    const int t = threadIdx.x;
    const int n0 = blockIdx.x * 16;
    {
        const float4* src = (const float4*)(h1 + (size_t)n0 * F1);
#pragma unroll
        for (int i = 0; i < 2; ++i) {
            int idx = t + 256 * i;
            float4 v = src[idx];
            int row = idx >> 5;
            int col = (idx & 31) * 4;
            ushort4 o = { f2bf(v.x), f2bf(v.y), f2bf(v.z), f2bf(v.w) };
            *(ushort4*)(xs + row * XPAD + col) = o;
        }
        const uint4* wsrc = (const uint4*)w2t;
#pragma unroll
        for (int i = 0; i < 4; ++i) {
            int idx = t + 256 * i;
            uint4 v = wsrc[idx];
            int row = idx >> 4;
            int col = (idx & 15) * 8;
            *(uint4*)(wls + row * XPAD + col) = v;
        }
    }
    __syncthreads();
    const int w = t >> 6;
    const int lane = t & 63;
    const int quad = lane >> 4;
    const int ncol = lane & 15;
    const int ch0 = w * 16;
    const unsigned short* arow = xs + ncol * XPAD;
    const unsigned short* brow = wls + (ch0 + ncol) * XPAD;
    f32x4 acc = {0.f, 0.f, 0.f, 0.f};
#pragma unroll
    for (int s = 0; s < 4; ++s) {
        int kb = s * 32 + quad * 8;
        short8 a = *(const short8*)(arow + kb);
        short8 b = *(const short8*)(brow + kb);
        acc = __builtin_amdgcn_mfma_f32_16x16x32_bf16(a, b, acc, 0, 0, 0);
    }
    const int ch = ch0 + ncol;
    const float asv = atts[ch] * LOG2E, adv = attd[ch] * LOG2E;  // pre-scale for exp2
#pragma unroll
    for (int reg = 0; reg < 4; ++reg) {
        const int m = quad * 4 + reg;
        float v = acc[reg];
        xwf8[(size_t)(n0 + m) * F2 + ch] = f2fp8(v);
        float ps = v * asv, pd = v * adv;
#pragma unroll
        for (int off = 1; off < 16; off <<= 1) {
            ps += __shfl_xor(ps, off);
            pd += __shfl_xor(pd, off);
        }
        if (ncol == 0) { parts[m][w] = ps; partd[m][w] = pd; }
    }
    __syncthreads();
    if (t < 16) {
        a2s[n0 + t] = (parts[t][0] + parts[t][1]) + (parts[t][2] + parts[t][3]);
        a2d[n0 + t] = (partd[t][0] + partd[t][1]) + (partd[t][2] + partd[t][3]);
    }
}

// ---------------- layer2 gather (round-2 form) --------------------------------
__global__ __launch_bounds__(256) void k_l2_gather(
    const int* __restrict__ rowstart, const int* __restrict__ csr,
    const int* __restrict__ deg, const float* __restrict__ a2s,
    const float* __restrict__ a2d, const unsigned* __restrict__ xwu,
    float* __restrict__ h2) {
    const int lane = threadIdx.x & 63;
    const int wid = threadIdx.x >> 6;
    const int n = blockIdx.x * 4 + wid;
    if (n >= N_NODES) return;
    const int rs = rowstart[n];
    const int nb16 = min((deg[n] + 15) >> 4, NB16_MAX);
    const int q = lane >> 4;
    const int sub = lane & 15;          // channel group 4*sub..4*sub+3
    const float adv = a2d[n];
    const int4* c4 = (const int4*)(csr + rs);
    vf2 f01 = {0.f, 0.f}, f23 = {0.f, 0.f};
    float den_l = 0.f;
    for (int b = 0; b < nb16; ++b) {
        int4 s4 = c4[4 * b + q];                 // edges 4q..4q+3
        int se = csr[rs + 16 * b + sub];         // weight edge = sub
        unsigned u0 = xwu[s4.x * 16 + sub], u1 = xwu[s4.y * 16 + sub];
        unsigned u2 = xwu[s4.z * 16 + sub], u3 = xwu[s4.w * 16 + sub];
        float sv = a2s[se] + adv;
        float we = fexp2(fmaxf(sv, NEG_SLOPE * sv));
        den_l += we;
        float w0 = __shfl(we, 4 * q + 0), w1 = __shfl(we, 4 * q + 1);
        float w2 = __shfl(we, 4 * q + 2), w3 = __shfl(we, 4 * q + 3);
        f01 = pkfma(w0, fp8lo(u0), f01); f23 = pkfma(w0, fp8hi(u0), f23);
        f01 = pkfma(w1, fp8lo(u1), f01); f23 = pkfma(w1, fp8hi(u1), f23);
        f01 = pkfma(w2, fp8lo(u2), f01); f23 = pkfma(w2, fp8hi(u2), f23);
        f01 = pkfma(w3, fp8lo(u3), f01); f23 = pkfma(w3, fp8hi(u3), f23);
    }
    float f0 = f01.x, f1 = f01.y, f2v = f23.x, f3 = f23.y;
#pragma unroll
    for (int off = 16; off <= 32; off <<= 1) {
        f0 += __shfl_xor(f0, off);
        f1 += __shfl_xor(f1, off);
        f2v += __shfl_xor(f2v, off);
        f3 += __shfl_xor(f3, off);
    }
#pragma unroll
    for (int off = 1; off <= 32; off <<= 1) den_l += __shfl_xor(den_l, off);
    if (lane < 16) {
        const float inv = 1.f / (0.25f * den_l + EPS_F);
        ((float4*)h2)[(size_t)n * 16 + sub] =
            make_float4(f0 * inv, f1 * inv, f2v * inv, f3 * inv);
    }
}

// ---------------- mean over nodes (fp64 accum) ----------------
#define MEAN_BLOCKS 256
__global__ __launch_bounds__(256) void k_mean(const float* __restrict__ h2,
                                              double* __restrict__ accum) {
    const int t = threadIdx.x;
    const int c = t & 63;
    double acc = 0.0;
    const size_t total = (size_t)N_NODES * F2;
    for (size_t idx = (size_t)blockIdx.x * 256 + t; idx < total; idx += (size_t)MEAN_BLOCKS * 256)
        acc += (double)h2[idx];
    __shared__ double red[256];
    red[t] = acc;
    __syncthreads();
    if (t < 64) {
        double v = red[t] + red[t + 64] + red[t + 128] + red[t + 192];
        atomicAdd(&accum[c], v);
    }
}

__global__ void k_final(const double* __restrict__ accum, const float* __restrict__ b2,
                        float* __restrict__ out) {
    int t = threadIdx.x;
    if (t < F2) out[t] = (float)(accum[t] * (1.0 / (double)N_NODES)) + b2[t];
}

// ---------------- launch ----------------
extern "C" void kernel_launch(void* const* d_in, const int* in_sizes, int n_in,
                              void* d_out, int out_size, void* d_ws, size_t ws_size,
                              hipStream_t stream) {
    (void)in_sizes; (void)n_in; (void)out_size; (void)ws_size;
    const float* x   = (const float*)d_in[0];
    const int*   ei  = (const int*)d_in[1];
    const float* W1  = (const float*)d_in[2];
    const float* as1 = (const float*)d_in[3];
    const float* ad1 = (const float*)d_in[4];
    const float* b1  = (const float*)d_in[5];
    const float* W2  = (const float*)d_in[6];
    const float* as2 = (const float*)d_in[7];
    const float* ad2 = (const float*)d_in[8];
    const float* b2  = (const float*)d_in[9];
    float* out = (float*)d_out;

    char* ws = (char*)d_ws;
    size_t off = 0;
    auto alloc = [&](size_t bytes) -> void* {
        void* p = ws + off;
        off += (bytes + 255) & ~(size_t)255;
        return p;
    };
    // accum and deg adjacent: one memset zeroes both
    double* accum   = (double*)alloc(F2 * 8);             // 512 B (rounded)
    int*   deg      = (int*)alloc((size_t)N_NODES * 4);
    unsigned char*  xw1f8 = (unsigned char*)alloc((size_t)(N_NODES + 1) * F1);
    float* h1       = (float*)alloc((size_t)N_NODES * F1 * 4);
    unsigned char*  xw2f8 = (unsigned char*)alloc((size_t)(N_NODES + 1) * F2);
    float* h2       = (float*)alloc((size_t)N_NODES * F2 * 4);
    unsigned short* w1t = (unsigned short*)alloc((size_t)F1 * F1 * 2);
    unsigned short* w2t = (unsigned short*)alloc((size_t)F2 * F1 * 2);
    float* a1s      = (float*)alloc((size_t)(N_NODES + 1) * H1 * 4);
    float* a1d      = (float*)alloc((size_t)N_NODES * H1 * 4);
    float* a2s      = (float*)alloc((size_t)(N_NODES + 1) * 4);
    float* a2d      = (float*)alloc((size_t)N_NODES * 4);
    int*   rowstart = (int*)alloc((size_t)(N_NODES + 1) * 4);
    int*   cur      = (int*)alloc((size_t)N_NODES * 4);
    int*   csr      = (int*)alloc((size_t)TEP * 4);
    int*   incl     = (int*)alloc((size_t)N_NODES * 4);
    int*   bsum     = (int*)alloc(64 * 4);

    const int nscan = (N_NODES + 1023) / 1024;  // 49
    const int nwave4 = (N_NODES + 3) / 4;       // 12500

    // zero accum (512B) + deg (200KB) in one call (adjacent allocations)
    hipMemsetAsync(accum, 0, 512 + (size_t)N_NODES * 4, stream);
    k_prep<<<96, 256, 0, stream>>>(W1, W2, w1t, w2t, a1s, a2s,
                                   (unsigned*)(xw1f8 + (size_t)SN * F1),
                                   (unsigned*)(xw2f8 + (size_t)SN * F2));
    k_l1_mm_hist<<<MM_BLOCKS + NBLK_A, 256, 0, stream>>>(x, w1t, as1, ad1, xw1f8, a1s, a1d, ei, deg);
    k_scan1<<<nscan, 1024, 0, stream>>>(deg, incl, bsum);
    k_scan3<<<nscan, 1024, 0, stream>>>(incl, bsum, deg, rowstart, cur, csr);
    k_scatter_direct<<<SC_BLOCKS, 256, 0, stream>>>(ei, cur, csr);
    k_l1_gather<<<nwave4, 256, 0, stream>>>(rowstart, csr, deg, a1s, a1d,
                                            (const unsigned*)xw1f8, b1, h1);
    k_l2_mm<<<MM_BLOCKS, 256, 0, stream>>>(h1, w2t, as2, ad2, xw2f8, a2s, a2d);
    k_l2_gather<<<nwave4, 256, 0, stream>>>(rowstart, csr, deg, a2s, a2d,
                                            (const unsigned*)xw2f8, h2);
    k_mean<<<MEAN_BLOCKS, 256, 0, stream>>>(h2, accum);
    k_final<<<1, 64, 0, stream>>>(accum, b2, out);
}

// Round 8
// 268.388 us; speedup vs baseline: 1.5203x; 1.5203x over previous
//
#include <hip/hip_runtime.h>
#include <math.h>

#define N_NODES 50000
#define SN      N_NODES               // sentinel node id for CSR pads
#define E_RAW   1600000
#define TE      (E_RAW + N_NODES)     // 1650000 edges incl. self loops
#define TEP     (TE + 16 * N_NODES)   // CSR padded to 16-aligned rows (upper bound)
#define F_IN    128
#define H1      4
#define F1      128                   // H1*C1
#define F2      64
#define NEG_SLOPE 0.2f
#define EPS_F   1e-16f
#define XPAD    136                   // LDS row stride in bf16 (kills bank conflicts)
#define LOG2E   1.4426950408889634f
#define NB16_MAX (TEP / 16)           // structural bound: no hang even if deg corrupt

// ---- bucket-sort CSR build params (all atomics are LDS-scope) ----
#define NBINS   196                   // coarse buckets: dst >> 8
#define NBLK_A  128                   // blocks in coarse hist/scatter
#define EPB     ((TE + NBLK_A - 1) / NBLK_A)
#define MM_BLOCKS (N_NODES / 16)      // 3125

typedef float vf2 __attribute__((ext_vector_type(2)));
typedef short short8 __attribute__((ext_vector_type(8)));
typedef float f32x4 __attribute__((ext_vector_type(4)));

__device__ __forceinline__ unsigned short f2bf(float f) {
    unsigned u = __float_as_uint(f);
    return (unsigned short)((u + 0x7fffu + ((u >> 16) & 1u)) >> 16);
}
__device__ __forceinline__ unsigned char f2fp8(float f) {
    int p = __builtin_amdgcn_cvt_pk_fp8_f32(f, f, 0, false);
    return (unsigned char)(p & 0xff);
}
__device__ __forceinline__ vf2 fp8lo(unsigned u) {   // bytes 0,1 -> 2 floats
    return __builtin_amdgcn_cvt_pk_f32_fp8((int)u, false);
}
__device__ __forceinline__ vf2 fp8hi(unsigned u) {   // bytes 2,3 -> 2 floats
    return __builtin_amdgcn_cvt_pk_f32_fp8((int)u, true);
}
// Packed dual-fp32 FMA; cvt_pk_f32_fp8 already yields float2.
__device__ __forceinline__ vf2 pkfma(float w, vf2 a, vf2 c) {
#if __has_builtin(__builtin_elementwise_fma)
    vf2 wv = {w, w};
    return __builtin_elementwise_fma(wv, a, c);
#else
    c.x = fmaf(w, a.x, c.x);
    c.y = fmaf(w, a.y, c.y);
    return c;
#endif
}
// Raw 2^x (attention logits pre-scaled by log2(e) in the matmul kernels).
__device__ __forceinline__ float fexp2(float x) {
#if __has_builtin(__builtin_amdgcn_exp2f)
    return __builtin_amdgcn_exp2f(x);
#else
    return exp2f(x);
#endif
}

// ---------------- prep: W -> transposed bf16 [c][k]; sentinel logits ---------
__global__ __launch_bounds__(256) void k_prep(const float* __restrict__ W1,
                                              const float* __restrict__ W2,
                                              unsigned short* __restrict__ w1t,
                                              unsigned short* __restrict__ w2t,
                                              float* __restrict__ a1s,
                                              float* __restrict__ a2s,
                                              unsigned* __restrict__ xw1row,
                                              unsigned* __restrict__ xw2row) {
    int idx = blockIdx.x * 256 + threadIdx.x;   // 96 blocks: 16384 + 8192
    if (idx < 16384) {
        int c = idx >> 7, k = idx & 127;
        w1t[idx] = f2bf(W1[k * F1 + c]);
    } else {
        int j = idx - 16384;
        int c = j >> 7, k = j & 127;
        w2t[j] = f2bf(W2[k * F2 + c]);
    }
    if (blockIdx.x == 0 && threadIdx.x < H1) a1s[SN * H1 + threadIdx.x] = -1e30f;
    if (blockIdx.x == 0 && threadIdx.x == H1) a2s[SN] = -1e30f;
    // zero sentinel xw rows: weight 0 * fp8-garbage could be 0*NaN otherwise
    if (blockIdx.x == 1) {
        if (threadIdx.x < 32) xw1row[threadIdx.x] = 0u;
        else if (threadIdx.x < 48) xw2row[threadIdx.x - 32] = 0u;
    }
}

// ---------------- layer1 matmul via MFMA (+ fused coarse histogram) ----------
__global__ __launch_bounds__(256) void k_l1_mm_hist(
    const float* __restrict__ x, const unsigned short* __restrict__ w1t,
    const float* __restrict__ atts, const float* __restrict__ attd,
    unsigned char* __restrict__ xwf8, float* __restrict__ a1s, float* __restrict__ a1d,
    const int* __restrict__ ei, int* __restrict__ cnt) {
    __shared__ __align__(16) unsigned short wls[F1 * XPAD];
    __shared__ __align__(16) unsigned short xs[16 * XPAD];
    const int t = threadIdx.x;
    if (blockIdx.x >= MM_BLOCKS) {
        int* hist = (int*)wls;
        const int blk = blockIdx.x - MM_BLOCKS;
        for (int i = t; i < NBINS; i += 256) hist[i] = 0;
        __syncthreads();
        const int e0 = blk * EPB, e1 = min(TE, e0 + EPB);
        for (int e = e0 + t; e < e1; e += 256) {
            int d = (e < E_RAW) ? ei[E_RAW + e] : (e - E_RAW);
            atomicAdd(&hist[d >> 8], 1);
        }
        __syncthreads();
        for (int i = t; i < NBINS; i += 256) cnt[i * NBLK_A + blk] = hist[i];
        return;
    }
    const int n0 = blockIdx.x * 16;
    {
        const float4* src = (const float4*)(x + (size_t)n0 * F_IN);
#pragma unroll
        for (int i = 0; i < 2; ++i) {
            int idx = t + 256 * i;
            float4 v = src[idx];
            int row = idx >> 5;
            int col = (idx & 31) * 4;
            ushort4 o = { f2bf(v.x), f2bf(v.y), f2bf(v.z), f2bf(v.w) };
            *(ushort4*)(xs + row * XPAD + col) = o;
        }
        const uint4* wsrc = (const uint4*)w1t;
#pragma unroll
        for (int i = 0; i < 8; ++i) {
            int idx = t + 256 * i;
            uint4 v = wsrc[idx];
            int row = idx >> 4;
            int col = (idx & 15) * 8;
            *(uint4*)(wls + row * XPAD + col) = v;
        }
    }
    __syncthreads();
    const int w = t >> 6;         // wave = head
    const int lane = t & 63;
    const int quad = lane >> 4;
    const int ncol = lane & 15;
    const int ch0 = w * 32;
    const unsigned short* arow = xs + ncol * XPAD;
    const unsigned short* brow0 = wls + (ch0 + ncol) * XPAD;
    const unsigned short* brow1 = brow0 + 16 * XPAD;
    f32x4 acc0 = {0.f, 0.f, 0.f, 0.f}, acc1 = {0.f, 0.f, 0.f, 0.f};
#pragma unroll
    for (int s = 0; s < 4; ++s) {
        int kb = s * 32 + quad * 8;
        short8 a  = *(const short8*)(arow + kb);
        short8 b0 = *(const short8*)(brow0 + kb);
        short8 b1 = *(const short8*)(brow1 + kb);
        acc0 = __builtin_amdgcn_mfma_f32_16x16x32_bf16(a, b0, acc0, 0, 0, 0);
        acc1 = __builtin_amdgcn_mfma_f32_16x16x32_bf16(a, b1, acc1, 0, 0, 0);
    }
    const int ch = ch0 + ncol;
    // logits pre-scaled by log2(e): gather kernels use bare v_exp_f32
    const float as0 = atts[ch] * LOG2E, as1 = atts[ch + 16] * LOG2E;
    const float ad0 = attd[ch] * LOG2E, ad1 = attd[ch + 16] * LOG2E;
#pragma unroll
    for (int reg = 0; reg < 4; ++reg) {
        const int n = n0 + quad * 4 + reg;
        float v0 = acc0[reg], v1 = acc1[reg];
        xwf8[(size_t)n * F1 + ch] = f2fp8(v0);
        xwf8[(size_t)n * F1 + ch + 16] = f2fp8(v1);
        float ps = fmaf(v0, as0, v1 * as1);
        float pd = fmaf(v0, ad0, v1 * ad1);
#pragma unroll
        for (int off = 1; off < 16; off <<= 1) {
            ps += __shfl_xor(ps, off);
            pd += __shfl_xor(pd, off);
        }
        if (ncol == 0) {
            a1s[n * H1 + w] = ps;
            a1d[n * H1 + w] = pd;
        }
    }
}

// ---------------- per-bin scan of cnt across blocks + bin totals -------------
__global__ __launch_bounds__(64) void k_btot(int* __restrict__ cnt, int* __restrict__ btot) {
    const int bin = blockIdx.x, lane = threadIdx.x;
    int c0 = cnt[bin * NBLK_A + 2 * lane];
    int c1 = cnt[bin * NBLK_A + 2 * lane + 1];
    int s = c0 + c1;
    int incl = s;
#pragma unroll
    for (int off = 1; off < 64; off <<= 1) {
        int u = __shfl_up(incl, off, 64);
        if (lane >= off) incl += u;
    }
    int excl = incl - s;
    cnt[bin * NBLK_A + 2 * lane] = excl;
    cnt[bin * NBLK_A + 2 * lane + 1] = excl + c0;
    if (lane == 63) btot[bin] = incl;
}

__global__ __launch_bounds__(64) void k_bstart(const int* __restrict__ btot,
                                               int* __restrict__ bstart) {
    const int lane = threadIdx.x;
    int v[4]; int s = 0;
#pragma unroll
    for (int j = 0; j < 4; ++j) {
        int i = 4 * lane + j;
        v[j] = (i < NBINS) ? btot[i] : 0;
        s += v[j];
    }
    int incl = s;
#pragma unroll
    for (int off = 1; off < 64; off <<= 1) {
        int u = __shfl_up(incl, off, 64);
        if (lane >= off) incl += u;
    }
    int run = incl - s;
#pragma unroll
    for (int j = 0; j < 4; ++j) {
        int i = 4 * lane + j;
        if (i < NBINS) bstart[i] = run;
        run += v[j];
    }
    if (lane == 63) bstart[NBINS] = TE;
}

// ---------------- scatter into coarse buckets (plain stores) -----------------
__global__ __launch_bounds__(256) void k_scatter_coarse(const int* __restrict__ ei,
                                                        const int* __restrict__ cnt,
                                                        const int* __restrict__ bstart,
                                                        unsigned* __restrict__ cbuf) {
    __shared__ int cur[NBINS];
    const int t = threadIdx.x, blk = blockIdx.x;
    for (int i = t; i < NBINS; i += 256) cur[i] = cnt[i * NBLK_A + blk] + bstart[i];
    __syncthreads();
    const int e0 = blk * EPB, e1 = min(TE, e0 + EPB);
    for (int e = e0 + t; e < e1; e += 256) {
        int s, d;
        if (e < E_RAW) { s = ei[e]; d = ei[E_RAW + e]; }
        else { s = e - E_RAW; d = s; }
        int pos = atomicAdd(&cur[d >> 8], 1);   // LDS atomic
        cbuf[pos] = ((unsigned)(d & 255) << 16) | (unsigned)s;
    }
}

// ---------------- fine histogram -> deg --------------------
__global__ __launch_bounds__(256) void k_fine_hist(const unsigned* __restrict__ cbuf,
                                                   const int* __restrict__ bstart,
                                                   int* __restrict__ deg) {
    __shared__ int hist[256];
    const int t = threadIdx.x, b = blockIdx.x;
    hist[t] = 0;
    __syncthreads();
    const int i0 = bstart[b], i1 = bstart[b + 1];
    for (int i = i0 + t; i < i1; i += 256) atomicAdd(&hist[cbuf[i] >> 16], 1);
    __syncthreads();
    const int d = b * 256 + t;
    if (d < N_NODES) deg[d] = hist[t];
}

// ---------------- exclusive scan over 16-PADDED degrees (2-level) ------------
__global__ __launch_bounds__(1024) void k_scan1(const int* __restrict__ deg,
                                                int* __restrict__ incl, int* __restrict__ bsum) {
    int t = threadIdx.x, g = blockIdx.x;
    int idx = g * 1024 + t;
    int v = (idx < N_NODES) ? ((deg[idx] + 15) & ~15) : 0;
    int lane = t & 63, w = t >> 6;
#pragma unroll
    for (int off = 1; off < 64; off <<= 1) {
        int u = __shfl_up(v, off, 64);
        if (lane >= off) v += u;
    }
    __shared__ int ws[16];
    if (lane == 63) ws[w] = v;
    __syncthreads();
    if (w == 0 && lane < 16) {
        int s = ws[lane];
#pragma unroll
        for (int off = 1; off < 16; off <<= 1) {
            int u = __shfl_up(s, off, 16);
            if (lane >= off) s += u;
        }
        ws[lane] = s;
    }
    __syncthreads();
    if (w > 0) v += ws[w - 1];
    if (idx < N_NODES) incl[idx] = v;
    if (t == 1023) bsum[g] = v;
}

// scan3 absorbs scan2: each block sums bsum[0..bid-1] itself (nscan=49<64)
__global__ __launch_bounds__(1024) void k_scan3(const int* __restrict__ incl,
                                                const int* __restrict__ bsum,
                                                int* __restrict__ rowstart) {
    __shared__ int soff;
    const int t = threadIdx.x;
    if (t < 64) {
        int v = (t < blockIdx.x) ? bsum[t] : 0;
#pragma unroll
        for (int off = 32; off >= 1; off >>= 1) v += __shfl_xor(v, off, 64);
        if (t == 0) soff = v;
    }
    __syncthreads();
    const int idx = blockIdx.x * 1024 + t;
    if (idx < N_NODES) rowstart[idx + 1] = incl[idx] + soff;
    if (idx == 0) rowstart[0] = 0;
}

// ---------------- per-bucket scatter into csr + sentinel pad fill ------------
__global__ __launch_bounds__(256) void k_build_csr(const unsigned* __restrict__ cbuf,
                                                   const int* __restrict__ bstart,
                                                   const int* __restrict__ rowstart,
                                                   const int* __restrict__ deg,
                                                   int* __restrict__ csr) {
    __shared__ int cur[256];
    const int t = threadIdx.x, b = blockIdx.x;
    const int d = b * 256 + t;
    cur[t] = (d < N_NODES) ? rowstart[d] : 0;
    __syncthreads();
    const int i0 = bstart[b], i1 = bstart[b + 1];
    for (int i = i0 + t; i < i1; i += 256) {
        unsigned v = cbuf[i];
        int pos = atomicAdd(&cur[v >> 16], 1);   // LDS atomic
        csr[pos] = (int)(v & 0xffffu);
    }
    __syncthreads();
    if (d < N_NODES) {
        const int pend = rowstart[d] + ((deg[d] + 15) & ~15);
        for (int i = cur[t]; i < pend; ++i) csr[i] = SN;
    }
}

// ---------------- layer1 gather (round-2 form: proven 42.5us, VGPR 32) -------
__global__ __launch_bounds__(256) void k_l1_gather(
    const int* __restrict__ rowstart, const int* __restrict__ csr,
    const int* __restrict__ deg, const float* __restrict__ a1s,
    const float* __restrict__ a1d, const unsigned* __restrict__ xwu,
    const float* __restrict__ b1, float* __restrict__ h1) {
    const int lane = threadIdx.x & 63;
    const int wid = threadIdx.x >> 6;
    const int n = blockIdx.x * 4 + wid;
    if (n >= N_NODES) return;
    const int rs = rowstart[n];
    const int nb16 = min((deg[n] + 15) >> 4, NB16_MAX);
    const int half = lane >> 5;
    const int sub = lane & 31;          // channel group 4*sub..4*sub+3
    const int h = sub >> 3;             // head
    const float adh = a1d[n * H1 + h];
    const int4* c4 = (const int4*)(csr + rs);
    const int eoff = half * 8 + (sub & 7);      // this lane's weight-edge in block
    const int wbase = half * 32 + (h << 3);     // octet's shuffle source base
    vf2 f01 = {0.f, 0.f}, f23 = {0.f, 0.f};
    float den_l = 0.f;
    for (int b = 0; b < nb16; ++b) {
        const int i0 = 4 * b + 2 * half;
        int4 sA = c4[i0], sB = c4[i0 + 1];
        int se = csr[rs + 16 * b + eoff];
        unsigned u0 = xwu[sA.x * 32 + sub], u1 = xwu[sA.y * 32 + sub];
        unsigned u2 = xwu[sA.z * 32 + sub], u3 = xwu[sA.w * 32 + sub];
        unsigned u4 = xwu[sB.x * 32 + sub], u5 = xwu[sB.y * 32 + sub];
        unsigned u6 = xwu[sB.z * 32 + sub], u7 = xwu[sB.w * 32 + sub];
        float sv = a1s[se * H1 + h] + adh;
        float we = fexp2(fmaxf(sv, NEG_SLOPE * sv));
        den_l += we;
        float w0 = __shfl(we, wbase + 0), w1 = __shfl(we, wbase + 1);
        float w2 = __shfl(we, wbase + 2), w3 = __shfl(we, wbase + 3);
        float w4 = __shfl(we, wbase + 4), w5 = __shfl(we, wbase + 5);
        float w6 = __shfl(we, wbase + 6), w7 = __shfl(we, wbase + 7);
        f01 = pkfma(w0, fp8lo(u0), f01); f23 = pkfma(w0, fp8hi(u0), f23);
        f01 = pkfma(w1, fp8lo(u1), f01); f23 = pkfma(w1, fp8hi(u1), f23);
        f01 = pkfma(w2, fp8lo(u2), f01); f23 = pkfma(w2, fp8hi(u2), f23);
        f01 = pkfma(w3, fp8lo(u3), f01); f23 = pkfma(w3, fp8hi(u3), f23);
        f01 = pkfma(w4, fp8lo(u4), f01); f23 = pkfma(w4, fp8hi(u4), f23);
        f01 = pkfma(w5, fp8lo(u5), f01); f23 = pkfma(w5, fp8hi(u5), f23);
        f01 = pkfma(w6, fp8lo(u6), f01); f23 = pkfma(w6, fp8hi(u6), f23);
        f01 = pkfma(w7, fp8lo(u7), f01); f23 = pkfma(w7, fp8hi(u7), f23);
    }
    float f0 = f01.x, f1 = f01.y, f2v = f23.x, f3 = f23.y;
    f0 += __shfl_xor(f0, 32);
    f1 += __shfl_xor(f1, 32);
    f2v += __shfl_xor(f2v, 32);
    f3 += __shfl_xor(f3, 32);
    den_l += __shfl_xor(den_l, 1);
    den_l += __shfl_xor(den_l, 2);
    den_l += __shfl_xor(den_l, 4);
    den_l += __shfl_xor(den_l, 32);
    if (half == 0) {
        const float inv = 1.f / (den_l + EPS_F);
        float4 bb = ((const float4*)b1)[sub];
        float o0 = fmaf(f0, inv, bb.x);
        float o1 = fmaf(f1, inv, bb.y);
        float o2 = fmaf(f2v, inv, bb.z);
        float o3 = fmaf(f3, inv, bb.w);
        o0 = o0 > 0.f ? o0 : expm1f(o0);
        o1 = o1 > 0.f ? o1 : expm1f(o1);
        o2 = o2 > 0.f ? o2 : expm1f(o2);
        o3 = o3 > 0.f ? o3 : expm1f(o3);
        ((float4*)h1)[(size_t)n * 32 + sub] = make_float4(o0, o1, o2, o3);
    }
}

// ---------------- layer2 matmul via MFMA (fp8 out, single head) --------------
__global__ __launch_bounds__(256) void k_l2_mm(
    const float* __restrict__ h1, const unsigned short* __restrict__ w2t,
    const float* __restrict__ atts, const float* __restrict__ attd,
    unsigned char* __restrict__ xwf8, float* __restrict__ a2s, float* __restrict__ a2d) {
    __shared__ __align__(16) unsigned short wls[F2 * XPAD];
    __shared__ __align__(16) unsigned short xs[16 * XPAD];
    __shared__ float parts[16][4], partd[16][4];
    const int t = threadIdx.x;
    const int n0 = blockIdx.x * 16;
    {
        const float4* src = (const float4*)(h1 + (size_t)n0 * F1);
#pragma unroll
        for (int i = 0; i < 2; ++i) {
            int idx = t + 256 * i;
            float4 v = src[idx];
            int row = idx >> 5;
            int col = (idx & 31) * 4;
            ushort4 o = { f2bf(v.x), f2bf(v.y), f2bf(v.z), f2bf(v.w) };
            *(ushort4*)(xs + row * XPAD + col) = o;
        }
        const uint4* wsrc = (const uint4*)w2t;
#pragma unroll
        for (int i = 0; i < 4; ++i) {
            int idx = t + 256 * i;
            uint4 v = wsrc[idx];
            int row = idx >> 4;
            int col = (idx & 15) * 8;
            *(uint4*)(wls + row * XPAD + col) = v;
        }
    }
    __syncthreads();
    const int w = t >> 6;
    const int lane = t & 63;
    const int quad = lane >> 4;
    const int ncol = lane & 15;
    const int ch0 = w * 16;
    const unsigned short* arow = xs + ncol * XPAD;
    const unsigned short* brow = wls + (ch0 + ncol) * XPAD;
    f32x4 acc = {0.f, 0.f, 0.f, 0.f};
#pragma unroll
    for (int s = 0; s < 4; ++s) {
        int kb = s * 32 + quad * 8;
        short8 a = *(const short8*)(arow + kb);
        short8 b = *(const short8*)(brow + kb);
        acc = __builtin_amdgcn_mfma_f32_16x16x32_bf16(a, b, acc, 0, 0, 0);
    }
    const int ch = ch0 + ncol;
    const float asv = atts[ch] * LOG2E, adv = attd[ch] * LOG2E;  // pre-scale for exp2
#pragma unroll
    for (int reg = 0; reg < 4; ++reg) {
        const int m = quad * 4 + reg;
        float v = acc[reg];
        xwf8[(size_t)(n0 + m) * F2 + ch] = f2fp8(v);
        float ps = v * asv, pd = v * adv;
#pragma unroll
        for (int off = 1; off < 16; off <<= 1) {
            ps += __shfl_xor(ps, off);
            pd += __shfl_xor(pd, off);
        }
        if (ncol == 0) { parts[m][w] = ps; partd[m][w] = pd; }
    }
    __syncthreads();
    if (t < 16) {
        a2s[n0 + t] = (parts[t][0] + parts[t][1]) + (parts[t][2] + parts[t][3]);
        a2d[n0 + t] = (partd[t][0] + partd[t][1]) + (partd[t][2] + partd[t][3]);
    }
}

// ---------------- layer2 gather (round-2 form) --------------------------------
__global__ __launch_bounds__(256) void k_l2_gather(
    const int* __restrict__ rowstart, const int* __restrict__ csr,
    const int* __restrict__ deg, const float* __restrict__ a2s,
    const float* __restrict__ a2d, const unsigned* __restrict__ xwu,
    float* __restrict__ h2) {
    const int lane = threadIdx.x & 63;
    const int wid = threadIdx.x >> 6;
    const int n = blockIdx.x * 4 + wid;
    if (n >= N_NODES) return;
    const int rs = rowstart[n];
    const int nb16 = min((deg[n] + 15) >> 4, NB16_MAX);
    const int q = lane >> 4;
    const int sub = lane & 15;          // channel group 4*sub..4*sub+3
    const float adv = a2d[n];
    const int4* c4 = (const int4*)(csr + rs);
    vf2 f01 = {0.f, 0.f}, f23 = {0.f, 0.f};
    float den_l = 0.f;
    for (int b = 0; b < nb16; ++b) {
        int4 s4 = c4[4 * b + q];                 // edges 4q..4q+3
        int se = csr[rs + 16 * b + sub];         // weight edge = sub
        unsigned u0 = xwu[s4.x * 16 + sub], u1 = xwu[s4.y * 16 + sub];
        unsigned u2 = xwu[s4.z * 16 + sub], u3 = xwu[s4.w * 16 + sub];
        float sv = a2s[se] + adv;
        float we = fexp2(fmaxf(sv, NEG_SLOPE * sv));
        den_l += we;
        float w0 = __shfl(we, 4 * q + 0), w1 = __shfl(we, 4 * q + 1);
        float w2 = __shfl(we, 4 * q + 2), w3 = __shfl(we, 4 * q + 3);
        f01 = pkfma(w0, fp8lo(u0), f01); f23 = pkfma(w0, fp8hi(u0), f23);
        f01 = pkfma(w1, fp8lo(u1), f01); f23 = pkfma(w1, fp8hi(u1), f23);
        f01 = pkfma(w2, fp8lo(u2), f01); f23 = pkfma(w2, fp8hi(u2), f23);
        f01 = pkfma(w3, fp8lo(u3), f01); f23 = pkfma(w3, fp8hi(u3), f23);
    }
    float f0 = f01.x, f1 = f01.y, f2v = f23.x, f3 = f23.y;
#pragma unroll
    for (int off = 16; off <= 32; off <<= 1) {
        f0 += __shfl_xor(f0, off);
        f1 += __shfl_xor(f1, off);
        f2v += __shfl_xor(f2v, off);
        f3 += __shfl_xor(f3, off);
    }
#pragma unroll
    for (int off = 1; off <= 32; off <<= 1) den_l += __shfl_xor(den_l, off);
    if (lane < 16) {
        const float inv = 1.f / (0.25f * den_l + EPS_F);
        ((float4*)h2)[(size_t)n * 16 + sub] =
            make_float4(f0 * inv, f1 * inv, f2v * inv, f3 * inv);
    }
}

// ---------------- mean over nodes (fp64 accum) ----------------
#define MEAN_BLOCKS 256
__global__ __launch_bounds__(256) void k_mean(const float* __restrict__ h2,
                                              double* __restrict__ accum) {
    const int t = threadIdx.x;
    const int c = t & 63;
    double acc = 0.0;
    const size_t total = (size_t)N_NODES * F2;
    for (size_t idx = (size_t)blockIdx.x * 256 + t; idx < total; idx += (size_t)MEAN_BLOCKS * 256)
        acc += (double)h2[idx];
    __shared__ double red[256];
    red[t] = acc;
    __syncthreads();
    if (t < 64) {
        double v = red[t] + red[t + 64] + red[t + 128] + red[t + 192];
        atomicAdd(&accum[c], v);
    }
}

__global__ void k_final(const double* __restrict__ accum, const float* __restrict__ b2,
                        float* __restrict__ out) {
    int t = threadIdx.x;
    if (t < F2) out[t] = (float)(accum[t] * (1.0 / (double)N_NODES)) + b2[t];
}

// ---------------- launch ----------------
extern "C" void kernel_launch(void* const* d_in, const int* in_sizes, int n_in,
                              void* d_out, int out_size, void* d_ws, size_t ws_size,
                              hipStream_t stream) {
    (void)in_sizes; (void)n_in; (void)out_size; (void)ws_size;
    const float* x   = (const float*)d_in[0];
    const int*   ei  = (const int*)d_in[1];
    const float* W1  = (const float*)d_in[2];
    const float* as1 = (const float*)d_in[3];
    const float* ad1 = (const float*)d_in[4];
    const float* b1  = (const float*)d_in[5];
    const float* W2  = (const float*)d_in[6];
    const float* as2 = (const float*)d_in[7];
    const float* ad2 = (const float*)d_in[8];
    const float* b2  = (const float*)d_in[9];
    float* out = (float*)d_out;

    char* ws = (char*)d_ws;
    size_t off = 0;
    auto alloc = [&](size_t bytes) -> void* {
        void* p = ws + off;
        off += (bytes + 255) & ~(size_t)255;
        return p;
    };
    unsigned char*  xw1f8 = (unsigned char*)alloc((size_t)(N_NODES + 1) * F1);
    float* h1       = (float*)alloc((size_t)N_NODES * F1 * 4);
    unsigned char*  xw2f8 = (unsigned char*)alloc((size_t)(N_NODES + 1) * F2);
    float* h2       = (float*)alloc((size_t)N_NODES * F2 * 4);
    unsigned short* w1t = (unsigned short*)alloc((size_t)F1 * F1 * 2);
    unsigned short* w2t = (unsigned short*)alloc((size_t)F2 * F1 * 2);
    float* a1s      = (float*)alloc((size_t)(N_NODES + 1) * H1 * 4);
    float* a1d      = (float*)alloc((size_t)N_NODES * H1 * 4);
    float* a2s      = (float*)alloc((size_t)(N_NODES + 1) * 4);
    float* a2d      = (float*)alloc((size_t)N_NODES * 4);
    int*   deg      = (int*)alloc((size_t)N_NODES * 4);
    unsigned* cbuf  = (unsigned*)alloc((size_t)TE * 4);
    int*   cnt      = (int*)alloc((size_t)NBINS * NBLK_A * 4);
    int*   btot     = (int*)alloc((size_t)NBINS * 4);
    int*   bstart   = (int*)alloc((size_t)(NBINS + 1) * 4);
    int*   rowstart = (int*)alloc((size_t)(N_NODES + 1) * 4);
    int*   csr      = (int*)alloc((size_t)TEP * 4);
    int*   incl     = (int*)alloc((size_t)N_NODES * 4);
    int*   bsum     = (int*)alloc(64 * 4);
    double* accum   = (double*)alloc(F2 * 8);

    const int nscan = (N_NODES + 1023) / 1024;  // 49
    const int nwave4 = (N_NODES + 3) / 4;       // 12500

    hipMemsetAsync(accum, 0, F2 * 8, stream);
    k_prep<<<96, 256, 0, stream>>>(W1, W2, w1t, w2t, a1s, a2s,
                                   (unsigned*)(xw1f8 + (size_t)SN * F1),
                                   (unsigned*)(xw2f8 + (size_t)SN * F2));
    k_l1_mm_hist<<<MM_BLOCKS + NBLK_A, 256, 0, stream>>>(x, w1t, as1, ad1, xw1f8, a1s, a1d, ei, cnt);
    k_btot<<<NBINS, 64, 0, stream>>>(cnt, btot);
    k_bstart<<<1, 64, 0, stream>>>(btot, bstart);
    k_scatter_coarse<<<NBLK_A, 256, 0, stream>>>(ei, cnt, bstart, cbuf);
    k_fine_hist<<<NBINS, 256, 0, stream>>>(cbuf, bstart, deg);
    k_scan1<<<nscan, 1024, 0, stream>>>(deg, incl, bsum);
    k_scan3<<<nscan, 1024, 0, stream>>>(incl, bsum, rowstart);
    k_build_csr<<<NBINS, 256, 0, stream>>>(cbuf, bstart, rowstart, deg, csr);
    k_l1_gather<<<nwave4, 256, 0, stream>>>(rowstart, csr, deg, a1s, a1d,
                                            (const unsigned*)xw1f8, b1, h1);
    k_l2_mm<<<MM_BLOCKS, 256, 0, stream>>>(h1, w2t, as2, ad2, xw2f8, a2s, a2d);
    k_l2_gather<<<nwave4, 256, 0, stream>>>(rowstart, csr, deg, a2s, a2d,
                                            (const unsigned*)xw2f8, h2);
    k_mean<<<MEAN_BLOCKS, 256, 0, stream>>>(h2, accum);
    k_final<<<1, 64, 0, stream>>>(accum, b2, out);
}

// Round 10
// 263.203 us; speedup vs baseline: 1.5502x; 1.0197x over previous
//
#include <hip/hip_runtime.h>
#include <math.h>

#define N_NODES 50000
#define SN      N_NODES               // sentinel node id for CSR pads
#define E_RAW   1600000
#define TE      (E_RAW + N_NODES)     // 1650000 edges incl. self loops
#define TEP     (TE + 16 * N_NODES)   // CSR padded to 16-aligned rows (upper bound)
#define F_IN    128
#define H1      4
#define F1      128                   // H1*C1
#define F2      64
#define NEG_SLOPE 0.2f
#define EPS_F   1e-16f
#define XPAD    136                   // LDS row stride in bf16 (kills bank conflicts)
#define LOG2E   1.4426950408889634f
#define NB16_MAX (TEP / 16)           // structural bound: no hang even if deg corrupt
#define NSCAN   ((N_NODES + 1023) / 1024)   // 49

// ---- bucket-sort CSR build params (all atomics are LDS-scope) ----
#define NBINS   196                   // coarse buckets: dst >> 8
#define NBLK_A  128                   // blocks in coarse hist/scatter
#define EPB     ((TE + NBLK_A - 1) / NBLK_A)
#define MM_BLOCKS (N_NODES / 16)      // 3125

typedef float vf2 __attribute__((ext_vector_type(2)));
typedef short short8 __attribute__((ext_vector_type(8)));
typedef float f32x4 __attribute__((ext_vector_type(4)));

__device__ __forceinline__ unsigned short f2bf(float f) {
    unsigned u = __float_as_uint(f);
    return (unsigned short)((u + 0x7fffu + ((u >> 16) & 1u)) >> 16);
}
__device__ __forceinline__ unsigned char f2fp8(float f) {
    int p = __builtin_amdgcn_cvt_pk_fp8_f32(f, f, 0, false);
    return (unsigned char)(p & 0xff);
}
__device__ __forceinline__ vf2 fp8lo(unsigned u) {   // bytes 0,1 -> 2 floats
    return __builtin_amdgcn_cvt_pk_f32_fp8((int)u, false);
}
__device__ __forceinline__ vf2 fp8hi(unsigned u) {   // bytes 2,3 -> 2 floats
    return __builtin_amdgcn_cvt_pk_f32_fp8((int)u, true);
}
// Packed dual-fp32 FMA; cvt_pk_f32_fp8 already yields float2.
__device__ __forceinline__ vf2 pkfma(float w, vf2 a, vf2 c) {
#if __has_builtin(__builtin_elementwise_fma)
    vf2 wv = {w, w};
    return __builtin_elementwise_fma(wv, a, c);
#else
    c.x = fmaf(w, a.x, c.x);
    c.y = fmaf(w, a.y, c.y);
    return c;
#endif
}
// Raw 2^x (attention logits pre-scaled by log2(e) in the matmul kernels).
__device__ __forceinline__ float fexp2(float x) {
#if __has_builtin(__builtin_amdgcn_exp2f)
    return __builtin_amdgcn_exp2f(x);
#else
    return exp2f(x);
#endif
}

// In-block exclusive scan of btot[0..NBINS) -> bs[0..NBINS], done by wave 0.
// (replaces the k_bstart dispatch; btot is 784B, L2-hot, ~100 cycles)
__device__ __forceinline__ void scan_btot(const int* __restrict__ btot,
                                          int* __restrict__ bs, int tid) {
    if (tid < 64) {
        int v[4]; int s = 0;
#pragma unroll
        for (int j = 0; j < 4; ++j) {
            int i = 4 * tid + j;
            v[j] = (i < NBINS) ? btot[i] : 0;
            s += v[j];
        }
        int incl = s;
#pragma unroll
        for (int off = 1; off < 64; off <<= 1) {
            int u = __shfl_up(incl, off, 64);
            if (tid >= off) incl += u;
        }
        int run = incl - s;
#pragma unroll
        for (int j = 0; j < 4; ++j) {
            int i = 4 * tid + j;
            if (i < NBINS) bs[i] = run;
            run += v[j];
        }
        if (tid == 63) bs[NBINS] = run;
    }
}

// ---------------- prep: W -> transposed bf16 [c][k]; sentinels; accum zero ---
__global__ __launch_bounds__(256) void k_prep(const float* __restrict__ W1,
                                              const float* __restrict__ W2,
                                              unsigned short* __restrict__ w1t,
                                              unsigned short* __restrict__ w2t,
                                              float* __restrict__ a1s,
                                              float* __restrict__ a2s,
                                              unsigned* __restrict__ xw1row,
                                              unsigned* __restrict__ xw2row,
                                              double* __restrict__ accum) {
    int idx = blockIdx.x * 256 + threadIdx.x;   // 96 blocks: 16384 + 8192
    if (idx < 16384) {
        int c = idx >> 7, k = idx & 127;
        w1t[idx] = f2bf(W1[k * F1 + c]);
    } else {
        int j = idx - 16384;
        int c = j >> 7, k = j & 127;
        w2t[j] = f2bf(W2[k * F2 + c]);
    }
    if (blockIdx.x == 0 && threadIdx.x < H1) a1s[SN * H1 + threadIdx.x] = -1e30f;
    if (blockIdx.x == 0 && threadIdx.x == H1) a2s[SN] = -1e30f;
    // zero sentinel xw rows: weight 0 * fp8-garbage could be 0*NaN otherwise
    if (blockIdx.x == 1) {
        if (threadIdx.x < 32) xw1row[threadIdx.x] = 0u;
        else if (threadIdx.x < 48) xw2row[threadIdx.x - 32] = 0u;
    }
    // zero the mean accumulator (replaces the hipMemsetAsync dispatch)
    if (blockIdx.x == 2 && threadIdx.x < F2) accum[threadIdx.x] = 0.0;
}

// ---------------- layer1 matmul via MFMA (+ fused coarse histogram) ----------
__global__ __launch_bounds__(256) void k_l1_mm_hist(
    const float* __restrict__ x, const unsigned short* __restrict__ w1t,
    const float* __restrict__ atts, const float* __restrict__ attd,
    unsigned char* __restrict__ xwf8, float* __restrict__ a1s, float* __restrict__ a1d,
    const int* __restrict__ ei, int* __restrict__ cnt) {
    __shared__ __align__(16) unsigned short wls[F1 * XPAD];
    __shared__ __align__(16) unsigned short xs[16 * XPAD];
    const int t = threadIdx.x;
    if (blockIdx.x >= MM_BLOCKS) {
        int* hist = (int*)wls;
        const int blk = blockIdx.x - MM_BLOCKS;
        for (int i = t; i < NBINS; i += 256) hist[i] = 0;
        __syncthreads();
        const int e0 = blk * EPB, e1 = min(TE, e0 + EPB);
        for (int e = e0 + t; e < e1; e += 256) {
            int d = (e < E_RAW) ? ei[E_RAW + e] : (e - E_RAW);
            atomicAdd(&hist[d >> 8], 1);
        }
        __syncthreads();
        for (int i = t; i < NBINS; i += 256) cnt[i * NBLK_A + blk] = hist[i];
        return;
    }
    const int n0 = blockIdx.x * 16;
    {
        const float4* src = (const float4*)(x + (size_t)n0 * F_IN);
#pragma unroll
        for (int i = 0; i < 2; ++i) {
            int idx = t + 256 * i;
            float4 v = src[idx];
            int row = idx >> 5;
            int col = (idx & 31) * 4;
            ushort4 o = { f2bf(v.x), f2bf(v.y), f2bf(v.z), f2bf(v.w) };
            *(ushort4*)(xs + row * XPAD + col) = o;
        }
        const uint4* wsrc = (const uint4*)w1t;
#pragma unroll
        for (int i = 0; i < 8; ++i) {
            int idx = t + 256 * i;
            uint4 v = wsrc[idx];
            int row = idx >> 4;
            int col = (idx & 15) * 8;
            *(uint4*)(wls + row * XPAD + col) = v;
        }
    }
    __syncthreads();
    const int w = t >> 6;         // wave = head
    const int lane = t & 63;
    const int quad = lane >> 4;
    const int ncol = lane & 15;
    const int ch0 = w * 32;
    const unsigned short* arow = xs + ncol * XPAD;
    const unsigned short* brow0 = wls + (ch0 + ncol) * XPAD;
    const unsigned short* brow1 = brow0 + 16 * XPAD;
    f32x4 acc0 = {0.f, 0.f, 0.f, 0.f}, acc1 = {0.f, 0.f, 0.f, 0.f};
#pragma unroll
    for (int s = 0; s < 4; ++s) {
        int kb = s * 32 + quad * 8;
        short8 a  = *(const short8*)(arow + kb);
        short8 b0 = *(const short8*)(brow0 + kb);
        short8 b1 = *(const short8*)(brow1 + kb);
        acc0 = __builtin_amdgcn_mfma_f32_16x16x32_bf16(a, b0, acc0, 0, 0, 0);
        acc1 = __builtin_amdgcn_mfma_f32_16x16x32_bf16(a, b1, acc1, 0, 0, 0);
    }
    const int ch = ch0 + ncol;
    // logits pre-scaled by log2(e): gather kernels use bare v_exp_f32
    const float as0 = atts[ch] * LOG2E, as1 = atts[ch + 16] * LOG2E;
    const float ad0 = attd[ch] * LOG2E, ad1 = attd[ch + 16] * LOG2E;
#pragma unroll
    for (int reg = 0; reg < 4; ++reg) {
        const int n = n0 + quad * 4 + reg;
        float v0 = acc0[reg], v1 = acc1[reg];
        xwf8[(size_t)n * F1 + ch] = f2fp8(v0);
        xwf8[(size_t)n * F1 + ch + 16] = f2fp8(v1);
        float ps = fmaf(v0, as0, v1 * as1);
        float pd = fmaf(v0, ad0, v1 * ad1);
#pragma unroll
        for (int off = 1; off < 16; off <<= 1) {
            ps += __shfl_xor(ps, off);
            pd += __shfl_xor(pd, off);
        }
        if (ncol == 0) {
            a1s[n * H1 + w] = ps;
            a1d[n * H1 + w] = pd;
        }
    }
}

// ---------------- per-bin scan of cnt across blocks + bin totals -------------
__global__ __launch_bounds__(64) void k_btot(int* __restrict__ cnt, int* __restrict__ btot) {
    const int bin = blockIdx.x, lane = threadIdx.x;
    int c0 = cnt[bin * NBLK_A + 2 * lane];
    int c1 = cnt[bin * NBLK_A + 2 * lane + 1];
    int s = c0 + c1;
    int incl = s;
#pragma unroll
    for (int off = 1; off < 64; off <<= 1) {
        int u = __shfl_up(incl, off, 64);
        if (lane >= off) incl += u;
    }
    int excl = incl - s;
    cnt[bin * NBLK_A + 2 * lane] = excl;
    cnt[bin * NBLK_A + 2 * lane + 1] = excl + c0;
    if (lane == 63) btot[bin] = incl;
}

// ---------------- scatter into coarse buckets (plain stores) -----------------
// (bstart recomputed in-block from btot -- k_bstart dispatch removed)
__global__ __launch_bounds__(256) void k_scatter_coarse(const int* __restrict__ ei,
                                                        const int* __restrict__ cnt,
                                                        const int* __restrict__ btot,
                                                        unsigned* __restrict__ cbuf) {
    __shared__ int cur[NBINS + 1];
    const int t = threadIdx.x, blk = blockIdx.x;
    scan_btot(btot, cur, t);
    __syncthreads();
    for (int i = t; i < NBINS; i += 256) cur[i] += cnt[i * NBLK_A + blk];
    __syncthreads();
    const int e0 = blk * EPB, e1 = min(TE, e0 + EPB);
    for (int e = e0 + t; e < e1; e += 256) {
        int s, d;
        if (e < E_RAW) { s = ei[e]; d = ei[E_RAW + e]; }
        else { s = e - E_RAW; d = s; }
        int pos = atomicAdd(&cur[d >> 8], 1);   // LDS atomic
        cbuf[pos] = ((unsigned)(d & 255) << 16) | (unsigned)s;
    }
}

// ---------------- fine histogram -> deg --------------------
__global__ __launch_bounds__(256) void k_fine_hist(const unsigned* __restrict__ cbuf,
                                                   const int* __restrict__ btot,
                                                   int* __restrict__ deg) {
    __shared__ int hist[256];
    __shared__ int bs[NBINS + 1];
    const int t = threadIdx.x, b = blockIdx.x;
    hist[t] = 0;
    scan_btot(btot, bs, t);
    __syncthreads();
    const int i0 = bs[b], i1 = bs[b + 1];
    for (int i = i0 + t; i < i1; i += 256) atomicAdd(&hist[cbuf[i] >> 16], 1);
    __syncthreads();
    const int d = b * 256 + t;
    if (d < N_NODES) deg[d] = hist[t];
}

// ---------------- exclusive scan over 16-PADDED degrees (2-level) ------------
__global__ __launch_bounds__(1024) void k_scan1(const int* __restrict__ deg,
                                                int* __restrict__ incl, int* __restrict__ bsum) {
    int t = threadIdx.x, g = blockIdx.x;
    int idx = g * 1024 + t;
    int v = (idx < N_NODES) ? ((deg[idx] + 15) & ~15) : 0;
    int lane = t & 63, w = t >> 6;
#pragma unroll
    for (int off = 1; off < 64; off <<= 1) {
        int u = __shfl_up(v, off, 64);
        if (lane >= off) v += u;
    }
    __shared__ int ws[16];
    if (lane == 63) ws[w] = v;
    __syncthreads();
    if (w == 0 && lane < 16) {
        int s = ws[lane];
#pragma unroll
        for (int off = 1; off < 16; off <<= 1) {
            int u = __shfl_up(s, off, 16);
            if (lane >= off) s += u;
        }
        ws[lane] = s;
    }
    __syncthreads();
    if (w > 0) v += ws[w - 1];
    if (idx < N_NODES) incl[idx] = v;
    if (t == 1023) bsum[g] = v;
}

// ---------------- per-bucket scatter into csr + rowstart + sentinel fill -----
// Absorbs the old k_scan3: computes rowstart[d] = incl[d-1] + prefix(bsum)
// in-block (wave 1 scans the 49 bsum entries), writes it for the gathers,
// then does the bucket scatter and pad fill as before.
__global__ __launch_bounds__(256) void k_build_csr(const unsigned* __restrict__ cbuf,
                                                   const int* __restrict__ btot,
                                                   const int* __restrict__ bsum,
                                                   const int* __restrict__ inclg,
                                                   const int* __restrict__ deg,
                                                   int* __restrict__ rowstart,
                                                   int* __restrict__ csr) {
    __shared__ int cur[256];
    __shared__ int bs[NBINS + 1];
    __shared__ int bp[64];
    const int t = threadIdx.x, b = blockIdx.x;
    scan_btot(btot, bs, t);
    if (t >= 64 && t < 128) {          // wave 1: exclusive prefix of bsum[0..NSCAN)
        const int lane = t - 64;
        int v = (lane < NSCAN) ? bsum[lane] : 0;
        int incl = v;
#pragma unroll
        for (int off = 1; off < 64; off <<= 1) {
            int u = __shfl_up(incl, off, 64);
            if (lane >= off) incl += u;
        }
        bp[lane] = incl - v;
    }
    __syncthreads();
    const int d = b * 256 + t;
    int rsv = 0;
    if (d < N_NODES) {
        if (d > 0) rsv = inclg[d - 1] + bp[(d - 1) >> 10];
        rowstart[d] = rsv;
    }
    cur[t] = rsv;
    __syncthreads();
    const int i0 = bs[b], i1 = bs[b + 1];
    for (int i = i0 + t; i < i1; i += 256) {
        unsigned v = cbuf[i];
        int pos = atomicAdd(&cur[v >> 16], 1);   // LDS atomic
        csr[pos] = (int)(v & 0xffffu);
    }
    __syncthreads();
    if (d < N_NODES) {
        const int pend = rsv + ((deg[d] + 15) & ~15);
        for (int i = cur[t]; i < pend; ++i) csr[i] = SN;
    }
}

// ---------------- layer1 gather (round-2 form: proven 42.5us, VGPR 32) -------
__global__ __launch_bounds__(256) void k_l1_gather(
    const int* __restrict__ rowstart, const int* __restrict__ csr,
    const int* __restrict__ deg, const float* __restrict__ a1s,
    const float* __restrict__ a1d, const unsigned* __restrict__ xwu,
    const float* __restrict__ b1, float* __restrict__ h1) {
    const int lane = threadIdx.x & 63;
    const int wid = threadIdx.x >> 6;
    const int n = blockIdx.x * 4 + wid;
    if (n >= N_NODES) return;
    const int rs = rowstart[n];
    const int nb16 = min((deg[n] + 15) >> 4, NB16_MAX);
    const int half = lane >> 5;
    const int sub = lane & 31;          // channel group 4*sub..4*sub+3
    const int h = sub >> 3;             // head
    const float adh = a1d[n * H1 + h];
    const int4* c4 = (const int4*)(csr + rs);
    const int eoff = half * 8 + (sub & 7);      // this lane's weight-edge in block
    const int wbase = half * 32 + (h << 3);     // octet's shuffle source base
    vf2 f01 = {0.f, 0.f}, f23 = {0.f, 0.f};
    float den_l = 0.f;
    for (int b = 0; b < nb16; ++b) {
        const int i0 = 4 * b + 2 * half;
        int4 sA = c4[i0], sB = c4[i0 + 1];
        int se = csr[rs + 16 * b + eoff];
        unsigned u0 = xwu[sA.x * 32 + sub], u1 = xwu[sA.y * 32 + sub];
        unsigned u2 = xwu[sA.z * 32 + sub], u3 = xwu[sA.w * 32 + sub];
        unsigned u4 = xwu[sB.x * 32 + sub], u5 = xwu[sB.y * 32 + sub];
        unsigned u6 = xwu[sB.z * 32 + sub], u7 = xwu[sB.w * 32 + sub];
        float sv = a1s[se * H1 + h] + adh;
        float we = fexp2(fmaxf(sv, NEG_SLOPE * sv));
        den_l += we;
        float w0 = __shfl(we, wbase + 0), w1 = __shfl(we, wbase + 1);
        float w2 = __shfl(we, wbase + 2), w3 = __shfl(we, wbase + 3);
        float w4 = __shfl(we, wbase + 4), w5 = __shfl(we, wbase + 5);
        float w6 = __shfl(we, wbase + 6), w7 = __shfl(we, wbase + 7);
        f01 = pkfma(w0, fp8lo(u0), f01); f23 = pkfma(w0, fp8hi(u0), f23);
        f01 = pkfma(w1, fp8lo(u1), f01); f23 = pkfma(w1, fp8hi(u1), f23);
        f01 = pkfma(w2, fp8lo(u2), f01); f23 = pkfma(w2, fp8hi(u2), f23);
        f01 = pkfma(w3, fp8lo(u3), f01); f23 = pkfma(w3, fp8hi(u3), f23);
        f01 = pkfma(w4, fp8lo(u4), f01); f23 = pkfma(w4, fp8hi(u4), f23);
        f01 = pkfma(w5, fp8lo(u5), f01); f23 = pkfma(w5, fp8hi(u5), f23);
        f01 = pkfma(w6, fp8lo(u6), f01); f23 = pkfma(w6, fp8hi(u6), f23);
        f01 = pkfma(w7, fp8lo(u7), f01); f23 = pkfma(w7, fp8hi(u7), f23);
    }
    float f0 = f01.x, f1 = f01.y, f2v = f23.x, f3 = f23.y;
    f0 += __shfl_xor(f0, 32);
    f1 += __shfl_xor(f1, 32);
    f2v += __shfl_xor(f2v, 32);
    f3 += __shfl_xor(f3, 32);
    den_l += __shfl_xor(den_l, 1);
    den_l += __shfl_xor(den_l, 2);
    den_l += __shfl_xor(den_l, 4);
    den_l += __shfl_xor(den_l, 32);
    if (half == 0) {
        const float inv = 1.f / (den_l + EPS_F);
        float4 bb = ((const float4*)b1)[sub];
        float o0 = fmaf(f0, inv, bb.x);
        float o1 = fmaf(f1, inv, bb.y);
        float o2 = fmaf(f2v, inv, bb.z);
        float o3 = fmaf(f3, inv, bb.w);
        o0 = o0 > 0.f ? o0 : expm1f(o0);
        o1 = o1 > 0.f ? o1 : expm1f(o1);
        o2 = o2 > 0.f ? o2 : expm1f(o2);
        o3 = o3 > 0.f ? o3 : expm1f(o3);
        ((float4*)h1)[(size_t)n * 32 + sub] = make_float4(o0, o1, o2, o3);
    }
}

// ---------------- layer2 matmul via MFMA (fp8 out, single head) --------------
__global__ __launch_bounds__(256) void k_l2_mm(
    const float* __restrict__ h1, const unsigned short* __restrict__ w2t,
    const float* __restrict__ atts, const float* __restrict__ attd,
    unsigned char* __restrict__ xwf8, float* __restrict__ a2s, float* __restrict__ a2d) {
    __shared__ __align__(16) unsigned short wls[F2 * XPAD];
    __shared__ __align__(16) unsigned short xs[16 * XPAD];
    __shared__ float parts[16][4], partd[16][4];
    const int t = threadIdx.x;
    const int n0 = blockIdx.x * 16;
    {
        const float4* src = (const float4*)(h1 + (size_t)n0 * F1);
#pragma unroll
        for (int i = 0; i < 2; ++i) {
            int idx = t + 256 * i;
            float4 v = src[idx];
            int row = idx >> 5;
            int col = (idx & 31) * 4;
            ushort4 o = { f2bf(v.x), f2bf(v.y), f2bf(v.z), f2bf(v.w) };
            *(ushort4*)(xs + row * XPAD + col) = o;
        }
        const uint4* wsrc = (const uint4*)w2t;
#pragma unroll
        for (int i = 0; i < 4; ++i) {
            int idx = t + 256 * i;
            uint4 v = wsrc[idx];
            int row = idx >> 4;
            int col = (idx & 15) * 8;
            *(uint4*)(wls + row * XPAD + col) = v;
        }
    }
    __syncthreads();
    const int w = t >> 6;
    const int lane = t & 63;
    const int quad = lane >> 4;
    const int ncol = lane & 15;
    const int ch0 = w * 16;
    const unsigned short* arow = xs + ncol * XPAD;
    const unsigned short* brow = wls + (ch0 + ncol) * XPAD;
    f32x4 acc = {0.f, 0.f, 0.f, 0.f};
#pragma unroll
    for (int s = 0; s < 4; ++s) {
        int kb = s * 32 + quad * 8;
        short8 a = *(const short8*)(arow + kb);
        short8 b = *(const short8*)(brow + kb);
        acc = __builtin_amdgcn_mfma_f32_16x16x32_bf16(a, b, acc, 0, 0, 0);
    }
    const int ch = ch0 + ncol;
    const float asv = atts[ch] * LOG2E, adv = attd[ch] * LOG2E;  // pre-scale for exp2
#pragma unroll
    for (int reg = 0; reg < 4; ++reg) {
        const int m = quad * 4 + reg;
        float v = acc[reg];
        xwf8[(size_t)(n0 + m) * F2 + ch] = f2fp8(v);
        float ps = v * asv, pd = v * adv;
#pragma unroll
        for (int off = 1; off < 16; off <<= 1) {
            ps += __shfl_xor(ps, off);
            pd += __shfl_xor(pd, off);
        }
        if (ncol == 0) { parts[m][w] = ps; partd[m][w] = pd; }
    }
    __syncthreads();
    if (t < 16) {
        a2s[n0 + t] = (parts[t][0] + parts[t][1]) + (parts[t][2] + parts[t][3]);
        a2d[n0 + t] = (partd[t][0] + partd[t][1]) + (partd[t][2] + partd[t][3]);
    }
}

// ---------------- layer2 gather (round-2 form) --------------------------------
__global__ __launch_bounds__(256) void k_l2_gather(
    const int* __restrict__ rowstart, const int* __restrict__ csr,
    const int* __restrict__ deg, const float* __restrict__ a2s,
    const float* __restrict__ a2d, const unsigned* __restrict__ xwu,
    float* __restrict__ h2) {
    const int lane = threadIdx.x & 63;
    const int wid = threadIdx.x >> 6;
    const int n = blockIdx.x * 4 + wid;
    if (n >= N_NODES) return;
    const int rs = rowstart[n];
    const int nb16 = min((deg[n] + 15) >> 4, NB16_MAX);
    const int q = lane >> 4;
    const int sub = lane & 15;          // channel group 4*sub..4*sub+3
    const float adv = a2d[n];
    const int4* c4 = (const int4*)(csr + rs);
    vf2 f01 = {0.f, 0.f}, f23 = {0.f, 0.f};
    float den_l = 0.f;
    for (int b = 0; b < nb16; ++b) {
        int4 s4 = c4[4 * b + q];                 // edges 4q..4q+3
        int se = csr[rs + 16 * b + sub];         // weight edge = sub
        unsigned u0 = xwu[s4.x * 16 + sub], u1 = xwu[s4.y * 16 + sub];
        unsigned u2 = xwu[s4.z * 16 + sub], u3 = xwu[s4.w * 16 + sub];
        float sv = a2s[se] + adv;
        float we = fexp2(fmaxf(sv, NEG_SLOPE * sv));
        den_l += we;
        float w0 = __shfl(we, 4 * q + 0), w1 = __shfl(we, 4 * q + 1);
        float w2 = __shfl(we, 4 * q + 2), w3 = __shfl(we, 4 * q + 3);
        f01 = pkfma(w0, fp8lo(u0), f01); f23 = pkfma(w0, fp8hi(u0), f23);
        f01 = pkfma(w1, fp8lo(u1), f01); f23 = pkfma(w1, fp8hi(u1), f23);
        f01 = pkfma(w2, fp8lo(u2), f01); f23 = pkfma(w2, fp8hi(u2), f23);
        f01 = pkfma(w3, fp8lo(u3), f01); f23 = pkfma(w3, fp8hi(u3), f23);
    }
    float f0 = f01.x, f1 = f01.y, f2v = f23.x, f3 = f23.y;
#pragma unroll
    for (int off = 16; off <= 32; off <<= 1) {
        f0 += __shfl_xor(f0, off);
        f1 += __shfl_xor(f1, off);
        f2v += __shfl_xor(f2v, off);
        f3 += __shfl_xor(f3, off);
    }
#pragma unroll
    for (int off = 1; off <= 32; off <<= 1) den_l += __shfl_xor(den_l, off);
    if (lane < 16) {
        const float inv = 1.f / (0.25f * den_l + EPS_F);
        ((float4*)h2)[(size_t)n * 16 + sub] =
            make_float4(f0 * inv, f1 * inv, f2v * inv, f3 * inv);
    }
}

// ---------------- mean over nodes (fp64 accum) ----------------
#define MEAN_BLOCKS 256
__global__ __launch_bounds__(256) void k_mean(const float* __restrict__ h2,
                                              double* __restrict__ accum) {
    const int t = threadIdx.x;
    const int c = t & 63;
    double acc = 0.0;
    const size_t total = (size_t)N_NODES * F2;
    for (size_t idx = (size_t)blockIdx.x * 256 + t; idx < total; idx += (size_t)MEAN_BLOCKS * 256)
        acc += (double)h2[idx];
    __shared__ double red[256];
    red[t] = acc;
    __syncthreads();
    if (t < 64) {
        double v = red[t] + red[t + 64] + red[t + 128] + red[t + 192];
        atomicAdd(&accum[c], v);
    }
}

__global__ void k_final(const double* __restrict__ accum, const float* __restrict__ b2,
                        float* __restrict__ out) {
    int t = threadIdx.x;
    if (t < F2) out[t] = (float)(accum[t] * (1.0 / (double)N_NODES)) + b2[t];
}

// ---------------- launch ----------------
extern "C" void kernel_launch(void* const* d_in, const int* in_sizes, int n_in,
                              void* d_out, int out_size, void* d_ws, size_t ws_size,
                              hipStream_t stream) {
    (void)in_sizes; (void)n_in; (void)out_size; (void)ws_size;
    const float* x   = (const float*)d_in[0];
    const int*   ei  = (const int*)d_in[1];
    const float* W1  = (const float*)d_in[2];
    const float* as1 = (const float*)d_in[3];
    const float* ad1 = (const float*)d_in[4];
    const float* b1  = (const float*)d_in[5];
    const float* W2  = (const float*)d_in[6];
    const float* as2 = (const float*)d_in[7];
    const float* ad2 = (const float*)d_in[8];
    const float* b2  = (const float*)d_in[9];
    float* out = (float*)d_out;

    char* ws = (char*)d_ws;
    size_t off = 0;
    auto alloc = [&](size_t bytes) -> void* {
        void* p = ws + off;
        off += (bytes + 255) & ~(size_t)255;
        return p;
    };
    unsigned char*  xw1f8 = (unsigned char*)alloc((size_t)(N_NODES + 1) * F1);
    float* h1       = (float*)alloc((size_t)N_NODES * F1 * 4);
    unsigned char*  xw2f8 = (unsigned char*)alloc((size_t)(N_NODES + 1) * F2);
    float* h2       = (float*)alloc((size_t)N_NODES * F2 * 4);
    unsigned short* w1t = (unsigned short*)alloc((size_t)F1 * F1 * 2);
    unsigned short* w2t = (unsigned short*)alloc((size_t)F2 * F1 * 2);
    float* a1s      = (float*)alloc((size_t)(N_NODES + 1) * H1 * 4);
    float* a1d      = (float*)alloc((size_t)N_NODES * H1 * 4);
    float* a2s      = (float*)alloc((size_t)(N_NODES + 1) * 4);
    float* a2d      = (float*)alloc((size_t)N_NODES * 4);
    int*   deg      = (int*)alloc((size_t)N_NODES * 4);
    unsigned* cbuf  = (unsigned*)alloc((size_t)TE * 4);
    int*   cnt      = (int*)alloc((size_t)NBINS * NBLK_A * 4);
    int*   btot     = (int*)alloc((size_t)NBINS * 4);
    int*   rowstart = (int*)alloc((size_t)(N_NODES + 1) * 4);
    int*   csr      = (int*)alloc((size_t)TEP * 4);
    int*   incl     = (int*)alloc((size_t)N_NODES * 4);
    int*   bsum     = (int*)alloc(64 * 4);
    double* accum   = (double*)alloc(F2 * 8);

    const int nscan = NSCAN;                    // 49
    const int nwave4 = (N_NODES + 3) / 4;       // 12500

    k_prep<<<96, 256, 0, stream>>>(W1, W2, w1t, w2t, a1s, a2s,
                                   (unsigned*)(xw1f8 + (size_t)SN * F1),
                                   (unsigned*)(xw2f8 + (size_t)SN * F2), accum);
    k_l1_mm_hist<<<MM_BLOCKS + NBLK_A, 256, 0, stream>>>(x, w1t, as1, ad1, xw1f8, a1s, a1d, ei, cnt);
    k_btot<<<NBINS, 64, 0, stream>>>(cnt, btot);
    k_scatter_coarse<<<NBLK_A, 256, 0, stream>>>(ei, cnt, btot, cbuf);
    k_fine_hist<<<NBINS, 256, 0, stream>>>(cbuf, btot, deg);
    k_scan1<<<nscan, 1024, 0, stream>>>(deg, incl, bsum);
    k_build_csr<<<NBINS, 256, 0, stream>>>(cbuf, btot, bsum, incl, deg, rowstart, csr);
    k_l1_gather<<<nwave4, 256, 0, stream>>>(rowstart, csr, deg, a1s, a1d,
                                            (const unsigned*)xw1f8, b1, h1);
    k_l2_mm<<<MM_BLOCKS, 256, 0, stream>>>(h1, w2t, as2, ad2, xw2f8, a2s, a2d);
    k_l2_gather<<<nwave4, 256, 0, stream>>>(rowstart, csr, deg, a2s, a2d,
                                            (const unsigned*)xw2f8, h2);
    k_mean<<<MEAN_BLOCKS, 256, 0, stream>>>(h2, accum);
    k_final<<<1, 64, 0, stream>>>(accum, b2, out);
}

// Round 11
// 256.259 us; speedup vs baseline: 1.5923x; 1.0271x over previous
//
#include <hip/hip_runtime.h>
#include <math.h>

#define N_NODES 50000
#define SN      N_NODES               // sentinel node id for CSR pads
#define E_RAW   1600000
#define TE      (E_RAW + N_NODES)     // 1650000 edges incl. self loops
#define TEP     (TE + 16 * N_NODES)   // CSR padded to 16-aligned rows (upper bound)
#define F_IN    128
#define H1      4
#define F1      128                   // H1*C1
#define F2      64
#define NEG_SLOPE 0.2f
#define EPS_F   1e-16f
#define XPAD    136                   // LDS row stride in bf16 (kills bank conflicts)
#define LOG2E   1.4426950408889634f
#define NB16_MAX (TEP / 16)           // structural bound: no hang even if deg corrupt
#define NSCAN   ((N_NODES + 1023) / 1024)   // 49
#define NWAVE4  ((N_NODES + 3) / 4)         // 12500 (exact: 50000 = 12500*4)

// ---- bucket-sort CSR build params (all atomics are LDS-scope) ----
#define NBINS   196                   // coarse buckets: dst >> 8
#define NBLK_A  128                   // blocks in coarse hist/scatter
#define EPB     ((TE + NBLK_A - 1) / NBLK_A)
#define MM_BLOCKS (N_NODES / 16)      // 3125

typedef float vf2 __attribute__((ext_vector_type(2)));
typedef short short8 __attribute__((ext_vector_type(8)));
typedef float f32x4 __attribute__((ext_vector_type(4)));

__device__ __forceinline__ unsigned short f2bf(float f) {
    unsigned u = __float_as_uint(f);
    return (unsigned short)((u + 0x7fffu + ((u >> 16) & 1u)) >> 16);
}
__device__ __forceinline__ unsigned char f2fp8(float f) {
    int p = __builtin_amdgcn_cvt_pk_fp8_f32(f, f, 0, false);
    return (unsigned char)(p & 0xff);
}
__device__ __forceinline__ vf2 fp8lo(unsigned u) {   // bytes 0,1 -> 2 floats
    return __builtin_amdgcn_cvt_pk_f32_fp8((int)u, false);
}
__device__ __forceinline__ vf2 fp8hi(unsigned u) {   // bytes 2,3 -> 2 floats
    return __builtin_amdgcn_cvt_pk_f32_fp8((int)u, true);
}
// Packed dual-fp32 FMA; cvt_pk_f32_fp8 already yields float2.
__device__ __forceinline__ vf2 pkfma(float w, vf2 a, vf2 c) {
#if __has_builtin(__builtin_elementwise_fma)
    vf2 wv = {w, w};
    return __builtin_elementwise_fma(wv, a, c);
#else
    c.x = fmaf(w, a.x, c.x);
    c.y = fmaf(w, a.y, c.y);
    return c;
#endif
}
// Raw 2^x (attention logits pre-scaled by log2(e) in the matmul kernels).
__device__ __forceinline__ float fexp2(float x) {
#if __has_builtin(__builtin_amdgcn_exp2f)
    return __builtin_amdgcn_exp2f(x);
#else
    return exp2f(x);
#endif
}

// In-block exclusive scan of btot[0..NBINS) -> bs[0..NBINS], done by wave 0.
__device__ __forceinline__ void scan_btot(const int* __restrict__ btot,
                                          int* __restrict__ bs, int tid) {
    if (tid < 64) {
        int v[4]; int s = 0;
#pragma unroll
        for (int j = 0; j < 4; ++j) {
            int i = 4 * tid + j;
            v[j] = (i < NBINS) ? btot[i] : 0;
            s += v[j];
        }
        int incl = s;
#pragma unroll
        for (int off = 1; off < 64; off <<= 1) {
            int u = __shfl_up(incl, off, 64);
            if (tid >= off) incl += u;
        }
        int run = incl - s;
#pragma unroll
        for (int j = 0; j < 4; ++j) {
            int i = 4 * tid + j;
            if (i < NBINS) bs[i] = run;
            run += v[j];
        }
        if (tid == 63) bs[NBINS] = run;
    }
}

// ---------------- prep: W -> transposed bf16 [c][k]; sentinels; accum zero ---
__global__ __launch_bounds__(256) void k_prep(const float* __restrict__ W1,
                                              const float* __restrict__ W2,
                                              unsigned short* __restrict__ w1t,
                                              unsigned short* __restrict__ w2t,
                                              float* __restrict__ a1s,
                                              float* __restrict__ a2s,
                                              unsigned* __restrict__ xw1row,
                                              unsigned* __restrict__ xw2row,
                                              double* __restrict__ accum) {
    int idx = blockIdx.x * 256 + threadIdx.x;   // 96 blocks: 16384 + 8192
    if (idx < 16384) {
        int c = idx >> 7, k = idx & 127;
        w1t[idx] = f2bf(W1[k * F1 + c]);
    } else {
        int j = idx - 16384;
        int c = j >> 7, k = j & 127;
        w2t[j] = f2bf(W2[k * F2 + c]);
    }
    if (blockIdx.x == 0 && threadIdx.x < H1) a1s[SN * H1 + threadIdx.x] = -1e30f;
    if (blockIdx.x == 0 && threadIdx.x == H1) a2s[SN] = -1e30f;
    // zero sentinel xw rows: weight 0 * fp8-garbage could be 0*NaN otherwise
    if (blockIdx.x == 1) {
        if (threadIdx.x < 32) xw1row[threadIdx.x] = 0u;
        else if (threadIdx.x < 48) xw2row[threadIdx.x - 32] = 0u;
    }
    // zero the mean accumulator (replaces the hipMemsetAsync dispatch)
    if (blockIdx.x == 2 && threadIdx.x < F2) accum[threadIdx.x] = 0.0;
}

// ---------------- layer1 matmul via MFMA (+ fused coarse histogram) ----------
__global__ __launch_bounds__(256) void k_l1_mm_hist(
    const float* __restrict__ x, const unsigned short* __restrict__ w1t,
    const float* __restrict__ atts, const float* __restrict__ attd,
    unsigned char* __restrict__ xwf8, float* __restrict__ a1s, float* __restrict__ a1d,
    const int* __restrict__ ei, int* __restrict__ cnt) {
    __shared__ __align__(16) unsigned short wls[F1 * XPAD];
    __shared__ __align__(16) unsigned short xs[16 * XPAD];
    const int t = threadIdx.x;
    if (blockIdx.x >= MM_BLOCKS) {
        int* hist = (int*)wls;
        const int blk = blockIdx.x - MM_BLOCKS;
        for (int i = t; i < NBINS; i += 256) hist[i] = 0;
        __syncthreads();
        const int e0 = blk * EPB, e1 = min(TE, e0 + EPB);
        for (int e = e0 + t; e < e1; e += 256) {
            int d = (e < E_RAW) ? ei[E_RAW + e] : (e - E_RAW);
            atomicAdd(&hist[d >> 8], 1);
        }
        __syncthreads();
        for (int i = t; i < NBINS; i += 256) cnt[i * NBLK_A + blk] = hist[i];
        return;
    }
    const int n0 = blockIdx.x * 16;
    {
        const float4* src = (const float4*)(x + (size_t)n0 * F_IN);
#pragma unroll
        for (int i = 0; i < 2; ++i) {
            int idx = t + 256 * i;
            float4 v = src[idx];
            int row = idx >> 5;
            int col = (idx & 31) * 4;
            ushort4 o = { f2bf(v.x), f2bf(v.y), f2bf(v.z), f2bf(v.w) };
            *(ushort4*)(xs + row * XPAD + col) = o;
        }
        const uint4* wsrc = (const uint4*)w1t;
#pragma unroll
        for (int i = 0; i < 8; ++i) {
            int idx = t + 256 * i;
            uint4 v = wsrc[idx];
            int row = idx >> 4;
            int col = (idx & 15) * 8;
            *(uint4*)(wls + row * XPAD + col) = v;
        }
    }
    __syncthreads();
    const int w = t >> 6;         // wave = head
    const int lane = t & 63;
    const int quad = lane >> 4;
    const int ncol = lane & 15;
    const int ch0 = w * 32;
    const unsigned short* arow = xs + ncol * XPAD;
    const unsigned short* brow0 = wls + (ch0 + ncol) * XPAD;
    const unsigned short* brow1 = brow0 + 16 * XPAD;
    f32x4 acc0 = {0.f, 0.f, 0.f, 0.f}, acc1 = {0.f, 0.f, 0.f, 0.f};
#pragma unroll
    for (int s = 0; s < 4; ++s) {
        int kb = s * 32 + quad * 8;
        short8 a  = *(const short8*)(arow + kb);
        short8 b0 = *(const short8*)(brow0 + kb);
        short8 b1 = *(const short8*)(brow1 + kb);
        acc0 = __builtin_amdgcn_mfma_f32_16x16x32_bf16(a, b0, acc0, 0, 0, 0);
        acc1 = __builtin_amdgcn_mfma_f32_16x16x32_bf16(a, b1, acc1, 0, 0, 0);
    }
    const int ch = ch0 + ncol;
    // logits pre-scaled by log2(e): gather kernels use bare v_exp_f32
    const float as0 = atts[ch] * LOG2E, as1 = atts[ch + 16] * LOG2E;
    const float ad0 = attd[ch] * LOG2E, ad1 = attd[ch + 16] * LOG2E;
#pragma unroll
    for (int reg = 0; reg < 4; ++reg) {
        const int n = n0 + quad * 4 + reg;
        float v0 = acc0[reg], v1 = acc1[reg];
        xwf8[(size_t)n * F1 + ch] = f2fp8(v0);
        xwf8[(size_t)n * F1 + ch + 16] = f2fp8(v1);
        float ps = fmaf(v0, as0, v1 * as1);
        float pd = fmaf(v0, ad0, v1 * ad1);
#pragma unroll
        for (int off = 1; off < 16; off <<= 1) {
            ps += __shfl_xor(ps, off);
            pd += __shfl_xor(pd, off);
        }
        if (ncol == 0) {
            a1s[n * H1 + w] = ps;
            a1d[n * H1 + w] = pd;
        }
    }
}

// ---------------- per-bin scan of cnt across blocks + bin totals -------------
__global__ __launch_bounds__(64) void k_btot(int* __restrict__ cnt, int* __restrict__ btot) {
    const int bin = blockIdx.x, lane = threadIdx.x;
    int c0 = cnt[bin * NBLK_A + 2 * lane];
    int c1 = cnt[bin * NBLK_A + 2 * lane + 1];
    int s = c0 + c1;
    int incl = s;
#pragma unroll
    for (int off = 1; off < 64; off <<= 1) {
        int u = __shfl_up(incl, off, 64);
        if (lane >= off) incl += u;
    }
    int excl = incl - s;
    cnt[bin * NBLK_A + 2 * lane] = excl;
    cnt[bin * NBLK_A + 2 * lane + 1] = excl + c0;
    if (lane == 63) btot[bin] = incl;
}

// ---------------- scatter into coarse buckets (plain stores) -----------------
__global__ __launch_bounds__(256) void k_scatter_coarse(const int* __restrict__ ei,
                                                        const int* __restrict__ cnt,
                                                        const int* __restrict__ btot,
                                                        unsigned* __restrict__ cbuf) {
    __shared__ int cur[NBINS + 1];
    const int t = threadIdx.x, blk = blockIdx.x;
    scan_btot(btot, cur, t);
    __syncthreads();
    for (int i = t; i < NBINS; i += 256) cur[i] += cnt[i * NBLK_A + blk];
    __syncthreads();
    const int e0 = blk * EPB, e1 = min(TE, e0 + EPB);
    for (int e = e0 + t; e < e1; e += 256) {
        int s, d;
        if (e < E_RAW) { s = ei[e]; d = ei[E_RAW + e]; }
        else { s = e - E_RAW; d = s; }
        int pos = atomicAdd(&cur[d >> 8], 1);   // LDS atomic
        cbuf[pos] = ((unsigned)(d & 255) << 16) | (unsigned)s;
    }
}

// ---------------- fine histogram -> deg --------------------
__global__ __launch_bounds__(256) void k_fine_hist(const unsigned* __restrict__ cbuf,
                                                   const int* __restrict__ btot,
                                                   int* __restrict__ deg) {
    __shared__ int hist[256];
    __shared__ int bs[NBINS + 1];
    const int t = threadIdx.x, b = blockIdx.x;
    hist[t] = 0;
    scan_btot(btot, bs, t);
    __syncthreads();
    const int i0 = bs[b], i1 = bs[b + 1];
    for (int i = i0 + t; i < i1; i += 256) atomicAdd(&hist[cbuf[i] >> 16], 1);
    __syncthreads();
    const int d = b * 256 + t;
    if (d < N_NODES) deg[d] = hist[t];
}

// ---------------- exclusive scan over 16-PADDED degrees (2-level) ------------
__global__ __launch_bounds__(1024) void k_scan1(const int* __restrict__ deg,
                                                int* __restrict__ incl, int* __restrict__ bsum) {
    int t = threadIdx.x, g = blockIdx.x;
    int idx = g * 1024 + t;
    int v = (idx < N_NODES) ? ((deg[idx] + 15) & ~15) : 0;
    int lane = t & 63, w = t >> 6;
#pragma unroll
    for (int off = 1; off < 64; off <<= 1) {
        int u = __shfl_up(v, off, 64);
        if (lane >= off) v += u;
    }
    __shared__ int ws[16];
    if (lane == 63) ws[w] = v;
    __syncthreads();
    if (w == 0 && lane < 16) {
        int s = ws[lane];
#pragma unroll
        for (int off = 1; off < 16; off <<= 1) {
            int u = __shfl_up(s, off, 16);
            if (lane >= off) s += u;
        }
        ws[lane] = s;
    }
    __syncthreads();
    if (w > 0) v += ws[w - 1];
    if (idx < N_NODES) incl[idx] = v;
    if (t == 1023) bsum[g] = v;
}

// ---------------- per-bucket scatter into csr + rowstart + sentinel fill -----
__global__ __launch_bounds__(256) void k_build_csr(const unsigned* __restrict__ cbuf,
                                                   const int* __restrict__ btot,
                                                   const int* __restrict__ bsum,
                                                   const int* __restrict__ inclg,
                                                   const int* __restrict__ deg,
                                                   int* __restrict__ rowstart,
                                                   int* __restrict__ csr) {
    __shared__ int cur[256];
    __shared__ int bs[NBINS + 1];
    __shared__ int bp[64];
    const int t = threadIdx.x, b = blockIdx.x;
    scan_btot(btot, bs, t);
    if (t >= 64 && t < 128) {          // wave 1: exclusive prefix of bsum[0..NSCAN)
        const int lane = t - 64;
        int v = (lane < NSCAN) ? bsum[lane] : 0;
        int incl = v;
#pragma unroll
        for (int off = 1; off < 64; off <<= 1) {
            int u = __shfl_up(incl, off, 64);
            if (lane >= off) incl += u;
        }
        bp[lane] = incl - v;
    }
    __syncthreads();
    const int d = b * 256 + t;
    int rsv = 0;
    if (d < N_NODES) {
        if (d > 0) rsv = inclg[d - 1] + bp[(d - 1) >> 10];
        rowstart[d] = rsv;
    }
    cur[t] = rsv;
    __syncthreads();
    const int i0 = bs[b], i1 = bs[b + 1];
    for (int i = i0 + t; i < i1; i += 256) {
        unsigned v = cbuf[i];
        int pos = atomicAdd(&cur[v >> 16], 1);   // LDS atomic
        csr[pos] = (int)(v & 0xffffu);
    }
    __syncthreads();
    if (d < N_NODES) {
        const int pend = rsv + ((deg[d] + 15) & ~15);
        for (int i = cur[t]; i < pend; ++i) csr[i] = SN;
    }
}

// ---------------- layer1 gather (round-2 form: proven 42.5us, VGPR 32) -------
__global__ __launch_bounds__(256) void k_l1_gather(
    const int* __restrict__ rowstart, const int* __restrict__ csr,
    const int* __restrict__ deg, const float* __restrict__ a1s,
    const float* __restrict__ a1d, const unsigned* __restrict__ xwu,
    const float* __restrict__ b1, float* __restrict__ h1) {
    const int lane = threadIdx.x & 63;
    const int wid = threadIdx.x >> 6;
    const int n = blockIdx.x * 4 + wid;
    if (n >= N_NODES) return;
    const int rs = rowstart[n];
    const int nb16 = min((deg[n] + 15) >> 4, NB16_MAX);
    const int half = lane >> 5;
    const int sub = lane & 31;          // channel group 4*sub..4*sub+3
    const int h = sub >> 3;             // head
    const float adh = a1d[n * H1 + h];
    const int4* c4 = (const int4*)(csr + rs);
    const int eoff = half * 8 + (sub & 7);      // this lane's weight-edge in block
    const int wbase = half * 32 + (h << 3);     // octet's shuffle source base
    vf2 f01 = {0.f, 0.f}, f23 = {0.f, 0.f};
    float den_l = 0.f;
    for (int b = 0; b < nb16; ++b) {
        const int i0 = 4 * b + 2 * half;
        int4 sA = c4[i0], sB = c4[i0 + 1];
        int se = csr[rs + 16 * b + eoff];
        unsigned u0 = xwu[sA.x * 32 + sub], u1 = xwu[sA.y * 32 + sub];
        unsigned u2 = xwu[sA.z * 32 + sub], u3 = xwu[sA.w * 32 + sub];
        unsigned u4 = xwu[sB.x * 32 + sub], u5 = xwu[sB.y * 32 + sub];
        unsigned u6 = xwu[sB.z * 32 + sub], u7 = xwu[sB.w * 32 + sub];
        float sv = a1s[se * H1 + h] + adh;
        float we = fexp2(fmaxf(sv, NEG_SLOPE * sv));
        den_l += we;
        float w0 = __shfl(we, wbase + 0), w1 = __shfl(we, wbase + 1);
        float w2 = __shfl(we, wbase + 2), w3 = __shfl(we, wbase + 3);
        float w4 = __shfl(we, wbase + 4), w5 = __shfl(we, wbase + 5);
        float w6 = __shfl(we, wbase + 6), w7 = __shfl(we, wbase + 7);
        f01 = pkfma(w0, fp8lo(u0), f01); f23 = pkfma(w0, fp8hi(u0), f23);
        f01 = pkfma(w1, fp8lo(u1), f01); f23 = pkfma(w1, fp8hi(u1), f23);
        f01 = pkfma(w2, fp8lo(u2), f01); f23 = pkfma(w2, fp8hi(u2), f23);
        f01 = pkfma(w3, fp8lo(u3), f01); f23 = pkfma(w3, fp8hi(u3), f23);
        f01 = pkfma(w4, fp8lo(u4), f01); f23 = pkfma(w4, fp8hi(u4), f23);
        f01 = pkfma(w5, fp8lo(u5), f01); f23 = pkfma(w5, fp8hi(u5), f23);
        f01 = pkfma(w6, fp8lo(u6), f01); f23 = pkfma(w6, fp8hi(u6), f23);
        f01 = pkfma(w7, fp8lo(u7), f01); f23 = pkfma(w7, fp8hi(u7), f23);
    }
    float f0 = f01.x, f1 = f01.y, f2v = f23.x, f3 = f23.y;
    f0 += __shfl_xor(f0, 32);
    f1 += __shfl_xor(f1, 32);
    f2v += __shfl_xor(f2v, 32);
    f3 += __shfl_xor(f3, 32);
    den_l += __shfl_xor(den_l, 1);
    den_l += __shfl_xor(den_l, 2);
    den_l += __shfl_xor(den_l, 4);
    den_l += __shfl_xor(den_l, 32);
    if (half == 0) {
        const float inv = 1.f / (den_l + EPS_F);
        float4 bb = ((const float4*)b1)[sub];
        float o0 = fmaf(f0, inv, bb.x);
        float o1 = fmaf(f1, inv, bb.y);
        float o2 = fmaf(f2v, inv, bb.z);
        float o3 = fmaf(f3, inv, bb.w);
        o0 = o0 > 0.f ? o0 : expm1f(o0);
        o1 = o1 > 0.f ? o1 : expm1f(o1);
        o2 = o2 > 0.f ? o2 : expm1f(o2);
        o3 = o3 > 0.f ? o3 : expm1f(o3);
        ((float4*)h1)[(size_t)n * 32 + sub] = make_float4(o0, o1, o2, o3);
    }
}

// ---------------- layer2 matmul via MFMA (fp8 out, single head) --------------
__global__ __launch_bounds__(256) void k_l2_mm(
    const float* __restrict__ h1, const unsigned short* __restrict__ w2t,
    const float* __restrict__ atts, const float* __restrict__ attd,
    unsigned char* __restrict__ xwf8, float* __restrict__ a2s, float* __restrict__ a2d) {
    __shared__ __align__(16) unsigned short wls[F2 * XPAD];
    __shared__ __align__(16) unsigned short xs[16 * XPAD];
    __shared__ float parts[16][4], partd[16][4];
    const int t = threadIdx.x;
    const int n0 = blockIdx.x * 16;
    {
        const float4* src = (const float4*)(h1 + (size_t)n0 * F1);
#pragma unroll
        for (int i = 0; i < 2; ++i) {
            int idx = t + 256 * i;
            float4 v = src[idx];
            int row = idx >> 5;
            int col = (idx & 31) * 4;
            ushort4 o = { f2bf(v.x), f2bf(v.y), f2bf(v.z), f2bf(v.w) };
            *(ushort4*)(xs + row * XPAD + col) = o;
        }
        const uint4* wsrc = (const uint4*)w2t;
#pragma unroll
        for (int i = 0; i < 4; ++i) {
            int idx = t + 256 * i;
            uint4 v = wsrc[idx];
            int row = idx >> 4;
            int col = (idx & 15) * 8;
            *(uint4*)(wls + row * XPAD + col) = v;
        }
    }
    __syncthreads();
    const int w = t >> 6;
    const int lane = t & 63;
    const int quad = lane >> 4;
    const int ncol = lane & 15;
    const int ch0 = w * 16;
    const unsigned short* arow = xs + ncol * XPAD;
    const unsigned short* brow = wls + (ch0 + ncol) * XPAD;
    f32x4 acc = {0.f, 0.f, 0.f, 0.f};
#pragma unroll
    for (int s = 0; s < 4; ++s) {
        int kb = s * 32 + quad * 8;
        short8 a = *(const short8*)(arow + kb);
        short8 b = *(const short8*)(brow + kb);
        acc = __builtin_amdgcn_mfma_f32_16x16x32_bf16(a, b, acc, 0, 0, 0);
    }
    const int ch = ch0 + ncol;
    const float asv = atts[ch] * LOG2E, adv = attd[ch] * LOG2E;  // pre-scale for exp2
#pragma unroll
    for (int reg = 0; reg < 4; ++reg) {
        const int m = quad * 4 + reg;
        float v = acc[reg];
        xwf8[(size_t)(n0 + m) * F2 + ch] = f2fp8(v);
        float ps = v * asv, pd = v * adv;
#pragma unroll
        for (int off = 1; off < 16; off <<= 1) {
            ps += __shfl_xor(ps, off);
            pd += __shfl_xor(pd, off);
        }
        if (ncol == 0) { parts[m][w] = ps; partd[m][w] = pd; }
    }
    __syncthreads();
    if (t < 16) {
        a2s[n0 + t] = (parts[t][0] + parts[t][1]) + (parts[t][2] + parts[t][3]);
        a2d[n0 + t] = (partd[t][0] + partd[t][1]) + (partd[t][2] + partd[t][3]);
    }
}

// ---------------- layer2 gather + per-block mean partial ----------------------
// h2 eliminated: it was only read by k_mean. Epilogue reduces the block's 4
// node-rows in LDS and emits one 64-float partial per block (pblk: 3.2 MB vs
// h2's 12.8 MB write + 12.8 MB read). Grid is exactly 12500*4 nodes, so the
// n-guard never fires and the __syncthreads is uniform.
__global__ __launch_bounds__(256) void k_l2_gather(
    const int* __restrict__ rowstart, const int* __restrict__ csr,
    const int* __restrict__ deg, const float* __restrict__ a2s,
    const float* __restrict__ a2d, const unsigned* __restrict__ xwu,
    float* __restrict__ pblk) {
    __shared__ float part[4][64];
    const int lane = threadIdx.x & 63;
    const int wid = threadIdx.x >> 6;
    const int n = blockIdx.x * 4 + wid;
    if (n >= N_NODES) return;           // never taken (grid exact); defensive
    const int rs = rowstart[n];
    const int nb16 = min((deg[n] + 15) >> 4, NB16_MAX);
    const int q = lane >> 4;
    const int sub = lane & 15;          // channel group 4*sub..4*sub+3
    const float adv = a2d[n];
    const int4* c4 = (const int4*)(csr + rs);
    vf2 f01 = {0.f, 0.f}, f23 = {0.f, 0.f};
    float den_l = 0.f;
    for (int b = 0; b < nb16; ++b) {
        int4 s4 = c4[4 * b + q];                 // edges 4q..4q+3
        int se = csr[rs + 16 * b + sub];         // weight edge = sub
        unsigned u0 = xwu[s4.x * 16 + sub], u1 = xwu[s4.y * 16 + sub];
        unsigned u2 = xwu[s4.z * 16 + sub], u3 = xwu[s4.w * 16 + sub];
        float sv = a2s[se] + adv;
        float we = fexp2(fmaxf(sv, NEG_SLOPE * sv));
        den_l += we;
        float w0 = __shfl(we, 4 * q + 0), w1 = __shfl(we, 4 * q + 1);
        float w2 = __shfl(we, 4 * q + 2), w3 = __shfl(we, 4 * q + 3);
        f01 = pkfma(w0, fp8lo(u0), f01); f23 = pkfma(w0, fp8hi(u0), f23);
        f01 = pkfma(w1, fp8lo(u1), f01); f23 = pkfma(w1, fp8hi(u1), f23);
        f01 = pkfma(w2, fp8lo(u2), f01); f23 = pkfma(w2, fp8hi(u2), f23);
        f01 = pkfma(w3, fp8lo(u3), f01); f23 = pkfma(w3, fp8hi(u3), f23);
    }
    float f0 = f01.x, f1 = f01.y, f2v = f23.x, f3 = f23.y;
#pragma unroll
    for (int off = 16; off <= 32; off <<= 1) {
        f0 += __shfl_xor(f0, off);
        f1 += __shfl_xor(f1, off);
        f2v += __shfl_xor(f2v, off);
        f3 += __shfl_xor(f3, off);
    }
#pragma unroll
    for (int off = 1; off <= 32; off <<= 1) den_l += __shfl_xor(den_l, off);
    if (lane < 16) {
        const float inv = 1.f / (0.25f * den_l + EPS_F);
        *(float4*)&part[wid][sub * 4] =
            make_float4(f0 * inv, f1 * inv, f2v * inv, f3 * inv);
    }
    __syncthreads();
    if (threadIdx.x < 64) {
        const int c = threadIdx.x;
        pblk[(size_t)blockIdx.x * 64 + c] =
            (part[0][c] + part[1][c]) + (part[2][c] + part[3][c]);
    }
}

// ---------------- mean over per-block partials (fp64 accum) ----------------
#define MEAN_BLOCKS 256
__global__ __launch_bounds__(256) void k_mean(const float* __restrict__ pblk,
                                              double* __restrict__ accum) {
    const int t = threadIdx.x;
    const int c = t & 63;
    double acc = 0.0;
    const size_t total = (size_t)NWAVE4 * F2;   // 800k floats (3.2 MB)
    for (size_t idx = (size_t)blockIdx.x * 256 + t; idx < total; idx += (size_t)MEAN_BLOCKS * 256)
        acc += (double)pblk[idx];               // stride keeps c = idx & 63 fixed
    __shared__ double red[256];
    red[t] = acc;
    __syncthreads();
    if (t < 64) {
        double v = red[t] + red[t + 64] + red[t + 128] + red[t + 192];
        atomicAdd(&accum[c], v);
    }
}

__global__ void k_final(const double* __restrict__ accum, const float* __restrict__ b2,
                        float* __restrict__ out) {
    int t = threadIdx.x;
    if (t < F2) out[t] = (float)(accum[t] * (1.0 / (double)N_NODES)) + b2[t];
}

// ---------------- launch ----------------
extern "C" void kernel_launch(void* const* d_in, const int* in_sizes, int n_in,
                              void* d_out, int out_size, void* d_ws, size_t ws_size,
                              hipStream_t stream) {
    (void)in_sizes; (void)n_in; (void)out_size; (void)ws_size;
    const float* x   = (const float*)d_in[0];
    const int*   ei  = (const int*)d_in[1];
    const float* W1  = (const float*)d_in[2];
    const float* as1 = (const float*)d_in[3];
    const float* ad1 = (const float*)d_in[4];
    const float* b1  = (const float*)d_in[5];
    const float* W2  = (const float*)d_in[6];
    const float* as2 = (const float*)d_in[7];
    const float* ad2 = (const float*)d_in[8];
    const float* b2  = (const float*)d_in[9];
    float* out = (float*)d_out;

    char* ws = (char*)d_ws;
    size_t off = 0;
    auto alloc = [&](size_t bytes) -> void* {
        void* p = ws + off;
        off += (bytes + 255) & ~(size_t)255;
        return p;
    };
    unsigned char*  xw1f8 = (unsigned char*)alloc((size_t)(N_NODES + 1) * F1);
    float* h1       = (float*)alloc((size_t)N_NODES * F1 * 4);
    unsigned char*  xw2f8 = (unsigned char*)alloc((size_t)(N_NODES + 1) * F2);
    float* pblk     = (float*)alloc((size_t)NWAVE4 * F2 * 4);   // replaces h2
    unsigned short* w1t = (unsigned short*)alloc((size_t)F1 * F1 * 2);
    unsigned short* w2t = (unsigned short*)alloc((size_t)F2 * F1 * 2);
    float* a1s      = (float*)alloc((size_t)(N_NODES + 1) * H1 * 4);
    float* a1d      = (float*)alloc((size_t)N_NODES * H1 * 4);
    float* a2s      = (float*)alloc((size_t)(N_NODES + 1) * 4);
    float* a2d      = (float*)alloc((size_t)N_NODES * 4);
    int*   deg      = (int*)alloc((size_t)N_NODES * 4);
    unsigned* cbuf  = (unsigned*)alloc((size_t)TE * 4);
    int*   cnt      = (int*)alloc((size_t)NBINS * NBLK_A * 4);
    int*   btot     = (int*)alloc((size_t)NBINS * 4);
    int*   rowstart = (int*)alloc((size_t)(N_NODES + 1) * 4);
    int*   csr      = (int*)alloc((size_t)TEP * 4);
    int*   incl     = (int*)alloc((size_t)N_NODES * 4);
    int*   bsum     = (int*)alloc(64 * 4);
    double* accum   = (double*)alloc(F2 * 8);

    const int nscan = NSCAN;                    // 49
    const int nwave4 = NWAVE4;                  // 12500

    k_prep<<<96, 256, 0, stream>>>(W1, W2, w1t, w2t, a1s, a2s,
                                   (unsigned*)(xw1f8 + (size_t)SN * F1),
                                   (unsigned*)(xw2f8 + (size_t)SN * F2), accum);
    k_l1_mm_hist<<<MM_BLOCKS + NBLK_A, 256, 0, stream>>>(x, w1t, as1, ad1, xw1f8, a1s, a1d, ei, cnt);
    k_btot<<<NBINS, 64, 0, stream>>>(cnt, btot);
    k_scatter_coarse<<<NBLK_A, 256, 0, stream>>>(ei, cnt, btot, cbuf);
    k_fine_hist<<<NBINS, 256, 0, stream>>>(cbuf, btot, deg);
    k_scan1<<<nscan, 1024, 0, stream>>>(deg, incl, bsum);
    k_build_csr<<<NBINS, 256, 0, stream>>>(cbuf, btot, bsum, incl, deg, rowstart, csr);
    k_l1_gather<<<nwave4, 256, 0, stream>>>(rowstart, csr, deg, a1s, a1d,
                                            (const unsigned*)xw1f8, b1, h1);
    k_l2_mm<<<MM_BLOCKS, 256, 0, stream>>>(h1, w2t, as2, ad2, xw2f8, a2s, a2d);
    k_l2_gather<<<nwave4, 256, 0, stream>>>(rowstart, csr, deg, a2s, a2d,
                                            (const unsigned*)xw2f8, pblk);
    k_mean<<<MEAN_BLOCKS, 256, 0, stream>>>(pblk, accum);
    k_final<<<1, 64, 0, stream>>>(accum, b2, out);
}